// Round 1
// baseline (558.022 us; speedup 1.0000x reference)
//
#include <hip/hip_runtime.h>

typedef unsigned short u16;
typedef unsigned int u32;
typedef __attribute__((ext_vector_type(8))) short bf16x8;
typedef __attribute__((ext_vector_type(4))) float f32x4;

#define NQ 4096      // B*N query tokens
#define NKV 1024     // B*M kv tokens
#define CDIM 2048
#define NHEADS 16
#define HDIM 128
#define QSCALE 0.08838834764831843f  // 1/sqrt(128)

__device__ __forceinline__ u16 f2bf(float f) {
  union { float f; u32 u; } a; a.f = f;
  u32 r = (a.u + 0x7fffu + ((a.u >> 16) & 1u)) >> 16;   // RNE
  return (u16)r;
}

// ---------------- fp32 -> bf16 flat convert (x4 vectorized) ----------------
__global__ __launch_bounds__(256) void k_f32_to_bf16(const float* __restrict__ in,
                                                     u16* __restrict__ out, int n4) {
  int i = blockIdx.x * 256 + threadIdx.x;
  if (i >= n4) return;
  float4 v = ((const float4*)in)[i];
  uint2 r;
  r.x = (u32)f2bf(v.x) | ((u32)f2bf(v.y) << 16);
  r.y = (u32)f2bf(v.z) | ((u32)f2bf(v.w) << 16);
  ((uint2*)out)[i] = r;
}

// ---------------- transpose fp32 (R x C) -> bf16 (C x R) ----------------
__global__ __launch_bounds__(256) void k_transpose_bf16(const float* __restrict__ in,
                                                        u16* __restrict__ out,
                                                        int R, int Ccols) {
  __shared__ float tile[32][33];
  int c0 = blockIdx.x * 32, r0 = blockIdx.y * 32;
  int tx = threadIdx.x & 31, ty = threadIdx.x >> 5;
#pragma unroll
  for (int i = 0; i < 4; ++i)
    tile[ty + i*8][tx] = in[(size_t)(r0 + ty + i*8) * Ccols + c0 + tx];
  __syncthreads();
#pragma unroll
  for (int i = 0; i < 4; ++i)
    out[(size_t)(c0 + ty + i*8) * R + r0 + tx] = f2bf(tile[tx][ty + i*8]);
}

// ---------------- bf16 MFMA GEMM: C(M,N) = A(M,K) @ Bt(N,K)^T + bias ----------------
// BM=BN=128, BK=32. 256 threads = 4 waves (2x2), each wave 4x4 tiles of 16x16x32.
// LDS stride 40 (=32+8) breaks the r*16%32 bank aliasing for the b128 frag reads.
__global__ __launch_bounds__(256) void k_gemm_bt(const u16* __restrict__ A,
                                                 const u16* __restrict__ Bt,
                                                 const float* __restrict__ bias,
                                                 float* __restrict__ Cout,
                                                 int Ndim, int Kdim) {
  __shared__ u16 As[128 * 40];
  __shared__ u16 Bs[128 * 40];
  const int bn = blockIdx.x, bm = blockIdx.y;
  const int t = threadIdx.x;
  const int lane = t & 63, w = t >> 6, quad = lane >> 4, l16 = lane & 15;
  const int wr = w >> 1, wc = w & 1;

  f32x4 acc[4][4];
#pragma unroll
  for (int i = 0; i < 4; ++i)
#pragma unroll
    for (int j = 0; j < 4; ++j) acc[i][j] = (f32x4){0.f, 0.f, 0.f, 0.f};

  // staging map: 512 segments of 16B per tile (128 rows x 4 chunks); 2 per thread
  const int r0a = t >> 2,        c0a = t & 3;
  const int r1a = (t + 256) >> 2, c1a = (t + 256) & 3;
  const u16* Ap = A + (size_t)(bm * 128) * Kdim;
  const u16* Bp = Bt + (size_t)(bn * 128) * Kdim;

  const int nkt = Kdim >> 5;
  for (int kt = 0; kt < nkt; ++kt) {
    const int kb = kt * 32;
    *(int4*)&As[r0a * 40 + c0a * 8] = *(const int4*)&Ap[(size_t)r0a * Kdim + kb + c0a * 8];
    *(int4*)&As[r1a * 40 + c1a * 8] = *(const int4*)&Ap[(size_t)r1a * Kdim + kb + c1a * 8];
    *(int4*)&Bs[r0a * 40 + c0a * 8] = *(const int4*)&Bp[(size_t)r0a * Kdim + kb + c0a * 8];
    *(int4*)&Bs[r1a * 40 + c1a * 8] = *(const int4*)&Bp[(size_t)r1a * Kdim + kb + c1a * 8];
    __syncthreads();
    bf16x8 af[4], bfr[4];
#pragma unroll
    for (int ti = 0; ti < 4; ++ti)
      af[ti] = *(const bf16x8*)&As[(wr*64 + ti*16 + l16) * 40 + quad*8];
#pragma unroll
    for (int tj = 0; tj < 4; ++tj)
      bfr[tj] = *(const bf16x8*)&Bs[(wc*64 + tj*16 + l16) * 40 + quad*8];
#pragma unroll
    for (int ti = 0; ti < 4; ++ti)
#pragma unroll
      for (int tj = 0; tj < 4; ++tj)
        acc[ti][tj] = __builtin_amdgcn_mfma_f32_16x16x32_bf16(af[ti], bfr[tj], acc[ti][tj], 0, 0, 0);
    __syncthreads();
  }
  // epilogue: C/D layout col=lane&15, row=quad*4+r (m89/m91-verified mapping)
#pragma unroll
  for (int ti = 0; ti < 4; ++ti) {
    int row = bm*128 + wr*64 + ti*16 + quad*4;
#pragma unroll
    for (int tj = 0; tj < 4; ++tj) {
      int col = bn*128 + wc*64 + tj*16 + l16;
      float bv = bias[col];
#pragma unroll
      for (int r = 0; r < 4; ++r)
        Cout[(size_t)(row + r) * Ndim + col] = acc[ti][tj][r] + bv;
    }
  }
}

// ---------------- per-128-group symmetric int8 fake-quant (q and k) ----------------
// one wave per group of 128 contiguous floats; 16 groups (heads) per row
__global__ __launch_bounds__(256) void k_quant_rows(const float* __restrict__ in,
                                                    u16* __restrict__ out,
                                                    int instride, int outstride,
                                                    float premul) {
  int wid = (blockIdx.x * 256 + threadIdx.x) >> 6;
  int lane = threadIdx.x & 63;
  int row = wid >> 4, g = wid & 15;
  const float* p = in + (size_t)row * instride + g * 128;
  float2 v = *(const float2*)(p + lane * 2);
  float vx = v.x * premul, vy = v.y * premul;
  float amax = fmaxf(fabsf(vx), fabsf(vy));
#pragma unroll
  for (int off = 32; off; off >>= 1) amax = fmaxf(amax, __shfl_xor(amax, off));
  float s = fmaxf(amax * (1.f / 127.f), 1e-8f);
  float qx = fminf(fmaxf(rintf(vx / s), -127.f), 127.f) * s;
  float qy = fminf(fmaxf(rintf(vy / s), -127.f), 127.f) * s;
  u32 packed = (u32)f2bf(qx) | ((u32)f2bf(qy) << 16);
  *(u32*)(out + (size_t)row * outstride + g * 128 + lane * 2) = packed;
}

__global__ __launch_bounds__(256) void k_zero(float* p, int n) {
  int i = blockIdx.x * 256 + threadIdx.x;
  if (i < n) p[i] = 0.f;
}

// ---------------- per-column |max| of V (columns = h*128+d, rows = 1024 tokens) ----------------
__global__ __launch_bounds__(256) void k_col_absmax(const float* __restrict__ in,
                                                    u32* __restrict__ vmax) {
  int c = blockIdx.x * 256 + threadIdx.x;
  int t0 = blockIdx.y * 64;
  float m = 0.f;
  for (int r = 0; r < 64; ++r)
    m = fmaxf(m, fabsf(in[(size_t)(t0 + r) * 4096 + c]));
  atomicMax(&vmax[c], __float_as_uint(m));   // all values >=0: uint order == float order
}

// ---------------- quantize V and write transposed: Vt[(h*128+d)][token] ----------------
__global__ __launch_bounds__(256) void k_vt_quant(const float* __restrict__ in,  // KVraw+2048, stride 4096
                                                  const float* __restrict__ vmax,
                                                  u16* __restrict__ Vt) {
  __shared__ float tile[32][33];
  int c0 = blockIdx.x * 32;  // d-columns
  int t0 = blockIdx.y * 32;  // tokens
  int tx = threadIdx.x & 31, ty = threadIdx.x >> 5;
#pragma unroll
  for (int i = 0; i < 4; ++i)
    tile[ty + i*8][tx] = in[(size_t)(t0 + ty + i*8) * 4096 + c0 + tx];
  __syncthreads();
#pragma unroll
  for (int i = 0; i < 4; ++i) {
    int d = ty + i*8;
    float s = fmaxf(vmax[c0 + d] * (1.f / 127.f), 1e-8f);
    float q = fminf(fmaxf(rintf(tile[tx][d] / s), -127.f), 127.f) * s;
    Vt[(size_t)(c0 + d) * 1024 + t0 + tx] = f2bf(q);
  }
}

// ---------------- fused attention: block = (head, 32 q-rows), 4 waves ----------------
// S kept in registers (32x1024 per block / 4 waves). u = rint(255*exp(s-m)) round-trips
// through a 64KB XOR-swizzled LDS buffer (C-layout -> A-layout transform), then PV MFMA.
__global__ __launch_bounds__(256) void k_attn(const u16* __restrict__ Qq,
                                              const u16* __restrict__ Kq,
                                              const u16* __restrict__ Vt,
                                              u16* __restrict__ O) {
  __shared__ u16 Ub[32 * 1024];               // exactly 64KB
  float* redmax = (float*)&Ub[0];             // [4][32], aliased (used before Ub written)
  float* redsum = (float*)&Ub[256];           // [4][32]

  const int h = blockIdx.y;
  const int r0 = blockIdx.x * 32;
  const int t = threadIdx.x;
  const int w = t >> 6, lane = t & 63, quad = lane >> 4, l16 = lane & 15;

  const u16* Qh = Qq + (size_t)r0 * 2048 + h * 128;
  const u16* Kh = Kq + h * 128;
  const u16* Vh = Vt + (size_t)h * 128 * 1024;

  // ---- S = Q K^T : wave w owns kv tokens [w*256, w*256+256) ----
  f32x4 s_acc[2][16];
#pragma unroll
  for (int ti = 0; ti < 2; ++ti)
#pragma unroll
    for (int tj = 0; tj < 16; ++tj) s_acc[ti][tj] = (f32x4){0.f, 0.f, 0.f, 0.f};

  for (int ks = 0; ks < 4; ++ks) {
    bf16x8 aq0 = *(const bf16x8*)&Qh[(size_t)(l16)      * 2048 + ks*32 + quad*8];
    bf16x8 aq1 = *(const bf16x8*)&Qh[(size_t)(16 + l16) * 2048 + ks*32 + quad*8];
#pragma unroll
    for (int tj = 0; tj < 16; ++tj) {
      bf16x8 bk = *(const bf16x8*)&Kh[(size_t)(w*256 + tj*16 + l16) * 2048 + ks*32 + quad*8];
      s_acc[0][tj] = __builtin_amdgcn_mfma_f32_16x16x32_bf16(aq0, bk, s_acc[0][tj], 0, 0, 0);
      s_acc[1][tj] = __builtin_amdgcn_mfma_f32_16x16x32_bf16(aq1, bk, s_acc[1][tj], 0, 0, 0);
    }
  }

  // lane's 8 rows: row = ti*16 + quad*4 + r
  float lmax[8];
#pragma unroll
  for (int ti = 0; ti < 2; ++ti)
#pragma unroll
    for (int r = 0; r < 4; ++r) {
      float m = -1e30f;
#pragma unroll
      for (int tj = 0; tj < 16; ++tj) m = fmaxf(m, s_acc[ti][tj][r]);
      lmax[ti*4 + r] = m;
    }
#pragma unroll
  for (int off = 1; off < 16; off <<= 1)
#pragma unroll
    for (int i = 0; i < 8; ++i) lmax[i] = fmaxf(lmax[i], __shfl_xor(lmax[i], off));
  if (l16 == 0)
#pragma unroll
    for (int i = 0; i < 8; ++i)
      redmax[w*32 + (i >> 2)*16 + quad*4 + (i & 3)] = lmax[i];
  __syncthreads();

  float gm[8], lsum[8];
#pragma unroll
  for (int i = 0; i < 8; ++i) {
    int row = (i >> 2)*16 + quad*4 + (i & 3);
    gm[i] = fmaxf(fmaxf(redmax[row], redmax[32 + row]),
                  fmaxf(redmax[64 + row], redmax[96 + row]));
    lsum[i] = 0.f;
  }
#pragma unroll
  for (int ti = 0; ti < 2; ++ti)
#pragma unroll
    for (int tj = 0; tj < 16; ++tj)
#pragma unroll
      for (int r = 0; r < 4; ++r)
        lsum[ti*4 + r] += __expf(s_acc[ti][tj][r] - gm[ti*4 + r]);
#pragma unroll
  for (int off = 1; off < 16; off <<= 1)
#pragma unroll
    for (int i = 0; i < 8; ++i) lsum[i] += __shfl_xor(lsum[i], off);
  if (l16 == 0)
#pragma unroll
    for (int i = 0; i < 8; ++i)
      redsum[w*32 + (i >> 2)*16 + quad*4 + (i & 3)] = lsum[i];
  __syncthreads();

  float rinv[8];
#pragma unroll
  for (int i = 0; i < 8; ++i) {
    int row = (i >> 2)*16 + quad*4 + (i & 3);
    float l = redsum[row] + redsum[32 + row] + redsum[64 + row] + redsum[96 + row];
    rinv[i] = 1.f / (255.f * l);   // s_p = max(p)/255 = 1/(255*l); 1e-8 floor can't bind
  }
  __syncthreads();   // all reads of red* done before Ub is clobbered

  // ---- u = rint(255*exp(s-m)) -> swizzled LDS (bf16 exact for ints <=255) ----
#pragma unroll
  for (int ti = 0; ti < 2; ++ti)
#pragma unroll
    for (int tj = 0; tj < 16; ++tj)
#pragma unroll
      for (int r = 0; r < 4; ++r) {
        int row = ti*16 + quad*4 + r;
        int col = w*256 + tj*16 + l16;
        float u = rintf(255.f * __expf(s_acc[ti][tj][r] - gm[ti*4 + r]));
        int chunk = col >> 3;
        Ub[row*1024 + ((chunk ^ (row & 7)) << 3) + (col & 7)] = f2bf(u);
      }
  __syncthreads();

  // ---- O = (U @ V) * rinv : wave w owns d-cols [w*32, w*32+32) ----
  f32x4 o_acc[2][2];
#pragma unroll
  for (int ti = 0; ti < 2; ++ti)
#pragma unroll
    for (int tj = 0; tj < 2; ++tj) o_acc[ti][tj] = (f32x4){0.f, 0.f, 0.f, 0.f};

  for (int ks = 0; ks < 32; ++ks) {
    bf16x8 au[2];
#pragma unroll
    for (int ti = 0; ti < 2; ++ti) {
      int row = ti*16 + l16;
      int chunk = ks*4 + quad;
      au[ti] = *(const bf16x8*)&Ub[row*1024 + ((chunk ^ (row & 7)) << 3)];
    }
#pragma unroll
    for (int tj = 0; tj < 2; ++tj) {
      bf16x8 bv = *(const bf16x8*)&Vh[(size_t)(w*32 + tj*16 + l16) * 1024 + ks*32 + quad*8];
      o_acc[0][tj] = __builtin_amdgcn_mfma_f32_16x16x32_bf16(au[0], bv, o_acc[0][tj], 0, 0, 0);
      o_acc[1][tj] = __builtin_amdgcn_mfma_f32_16x16x32_bf16(au[1], bv, o_acc[1][tj], 0, 0, 0);
    }
  }
#pragma unroll
  for (int ti = 0; ti < 2; ++ti)
#pragma unroll
    for (int tj = 0; tj < 2; ++tj)
#pragma unroll
      for (int r = 0; r < 4; ++r) {
        int row = ti*16 + quad*4 + r;
        int d = w*32 + tj*16 + l16;
        O[(size_t)(r0 + row) * 2048 + h*128 + d] = f2bf(o_acc[ti][tj][r] * rinv[ti*4 + r]);
      }
}

extern "C" void kernel_launch(void* const* d_in, const int* in_sizes, int n_in,
                              void* d_out, int out_size, void* d_ws, size_t ws_size,
                              hipStream_t stream) {
  const float* x    = (const float*)d_in[0];
  const float* cond = (const float*)d_in[1];
  const float* Wq   = (const float*)d_in[2];
  const float* bq   = (const float*)d_in[3];
  const float* Wkv  = (const float*)d_in[4];
  const float* bkv  = (const float*)d_in[5];
  const float* Wp   = (const float*)d_in[6];
  const float* bp   = (const float*)d_in[7];
  float* out = (float*)d_out;

  char* ws = (char*)d_ws;
  size_t off = 0;
  auto alloc = [&](size_t bytes) -> char* {
    char* p = ws + off;
    off += (bytes + 255) & ~(size_t)255;
    return p;
  };
  u16*   Xb    = (u16*)alloc((size_t)NQ * CDIM * 2);        // x in bf16
  u16*   Cb    = (u16*)alloc((size_t)NKV * CDIM * 2);       // cond in bf16
  u16*   WqT   = (u16*)alloc((size_t)CDIM * CDIM * 2);      // Wq^T (N,K) bf16
  u16*   WkvT  = (u16*)alloc((size_t)2 * CDIM * CDIM * 2);  // Wkv^T (4096,2048) bf16
  u16*   WpT   = (u16*)alloc((size_t)CDIM * CDIM * 2);      // Wp^T bf16
  float* Qraw  = (float*)alloc((size_t)NQ * CDIM * 4);      // x@Wq + bq
  float* KVraw = (float*)alloc((size_t)NKV * 2 * CDIM * 4); // cond@Wkv + bkv
  u16*   Qq    = (u16*)alloc((size_t)NQ * CDIM * 2);        // fake-quant q (scaled), bf16
  u16*   Kq    = (u16*)alloc((size_t)NKV * CDIM * 2);       // fake-quant k, bf16
  u16*   Vt    = (u16*)alloc((size_t)CDIM * NKV * 2);       // fake-quant v, transposed (h*128+d, token)
  float* vmax  = (float*)alloc((size_t)CDIM * 4);           // per-(h,d) |max| of v
  u16*   Ob    = (u16*)alloc((size_t)NQ * CDIM * 2);        // attention output, bf16
  // total ~140 MiB of d_ws

  // 1. bf16 converts of activations
  k_f32_to_bf16<<<NQ * CDIM / 4 / 256, 256, 0, stream>>>(x, Xb, NQ * CDIM / 4);
  k_f32_to_bf16<<<NKV * CDIM / 4 / 256, 256, 0, stream>>>(cond, Cb, NKV * CDIM / 4);
  // 2. weight transposes (fp32 -> bf16, (K,N) -> (N,K))
  k_transpose_bf16<<<dim3(CDIM/32, CDIM/32), 256, 0, stream>>>(Wq, WqT, CDIM, CDIM);
  k_transpose_bf16<<<dim3(2*CDIM/32, CDIM/32), 256, 0, stream>>>(Wkv, WkvT, CDIM, 2*CDIM);
  k_transpose_bf16<<<dim3(CDIM/32, CDIM/32), 256, 0, stream>>>(Wp, WpT, CDIM, CDIM);
  // 3. projections (bf16 MFMA, fp32 out + bias)
  k_gemm_bt<<<dim3(CDIM/128, NQ/128), 256, 0, stream>>>(Xb, WqT, bq, Qraw, CDIM, CDIM);
  k_gemm_bt<<<dim3(2*CDIM/128, NKV/128), 256, 0, stream>>>(Cb, WkvT, bkv, KVraw, 2*CDIM, CDIM);
  // 4. fake-quant q (with 1/sqrt(hd) pre-scale) and k, per (token, head)
  k_quant_rows<<<NQ * NHEADS / 4, 256, 0, stream>>>(Qraw, Qq, CDIM, CDIM, QSCALE);
  k_quant_rows<<<NKV * NHEADS / 4, 256, 0, stream>>>(KVraw, Kq, 2*CDIM, CDIM, 1.0f);
  // 5. fake-quant v per (head, dim) over tokens; store transposed
  k_zero<<<(CDIM + 255) / 256, 256, 0, stream>>>(vmax, CDIM);
  k_col_absmax<<<dim3(CDIM/256, NKV/64), 256, 0, stream>>>(KVraw + CDIM, (u32*)vmax);
  k_vt_quant<<<dim3(CDIM/32, NKV/32), 256, 0, stream>>>(KVraw + CDIM, vmax, Vt);
  // 6. fused quantized attention
  k_attn<<<dim3(NQ/32, NHEADS), 256, 0, stream>>>(Qq, Kq, Vt, Ob);
  // 7. output projection -> d_out (fp32)
  k_gemm_bt<<<dim3(CDIM/128, NQ/128), 256, 0, stream>>>(Ob, WpT, bp, out, CDIM, CDIM);
}

// Round 2
// 541.547 us; speedup vs baseline: 1.0304x; 1.0304x over previous
//
#include <hip/hip_runtime.h>

typedef unsigned short u16;
typedef unsigned int u32;
typedef __attribute__((ext_vector_type(8))) short bf16x8;
typedef __attribute__((ext_vector_type(4))) float f32x4;

#define NQ 4096      // B*N query tokens
#define NKV 1024     // B*M kv tokens
#define CDIM 2048
#define NHEADS 16
#define HDIM 128
#define QSCALE 0.08838834764831843f  // 1/sqrt(128)

#define GLOAD_LDS16(g, l) __builtin_amdgcn_global_load_lds( \
    (const __attribute__((address_space(1))) unsigned int*)(g), \
    (__attribute__((address_space(3))) unsigned int*)(l), 16, 0, 0)

__device__ __forceinline__ u16 f2bf(float f) {
  union { float f; u32 u; } a; a.f = f;
  u32 r = (a.u + 0x7fffu + ((a.u >> 16) & 1u)) >> 16;   // RNE
  return (u16)r;
}

// ---------------- fp32 -> bf16 flat convert (x4 vectorized) ----------------
__global__ __launch_bounds__(256) void k_f32_to_bf16(const float* __restrict__ in,
                                                     u16* __restrict__ out, int n4) {
  int i = blockIdx.x * 256 + threadIdx.x;
  if (i >= n4) return;
  float4 v = ((const float4*)in)[i];
  uint2 r;
  r.x = (u32)f2bf(v.x) | ((u32)f2bf(v.y) << 16);
  r.y = (u32)f2bf(v.z) | ((u32)f2bf(v.w) << 16);
  ((uint2*)out)[i] = r;
}

// ---------------- transpose fp32 (R x C) -> bf16 (C x R) ----------------
__global__ __launch_bounds__(256) void k_transpose_bf16(const float* __restrict__ in,
                                                        u16* __restrict__ out,
                                                        int R, int Ccols) {
  __shared__ float tile[32][33];
  int c0 = blockIdx.x * 32, r0 = blockIdx.y * 32;
  int tx = threadIdx.x & 31, ty = threadIdx.x >> 5;
#pragma unroll
  for (int i = 0; i < 4; ++i)
    tile[ty + i*8][tx] = in[(size_t)(r0 + ty + i*8) * Ccols + c0 + tx];
  __syncthreads();
#pragma unroll
  for (int i = 0; i < 4; ++i)
    out[(size_t)(c0 + ty + i*8) * R + r0 + tx] = f2bf(tile[tx][ty + i*8]);
}

// ---------------- bf16 MFMA GEMM: C(M,N) = A(M,K) @ Bt(N,K)^T + bias ----------------
// m97 structure: BM=BN=128, BK=32, 4 waves, 4x4 16x16x32 frags/wave,
// global_load_lds width=16 staging into UNPADDED stride-32 LDS tiles
// (wave-uniform base + lane*16 contiguity requirement -> no padding allowed).
__global__ __launch_bounds__(256) void k_gemm_bt(const u16* __restrict__ A,
                                                 const u16* __restrict__ Bt,
                                                 const float* __restrict__ bias,
                                                 float* __restrict__ Cout,
                                                 int Ndim, int Kdim) {
  __shared__ u16 As[128 * 32];
  __shared__ u16 Bs[128 * 32];
  const int bn = blockIdx.x, bm = blockIdx.y;
  const int t = threadIdx.x;
  const int lane = t & 63, w = t >> 6, quad = lane >> 4, l16 = lane & 15;
  const int wr = w >> 1, wc = w & 1;

  f32x4 acc[4][4];
#pragma unroll
  for (int i = 0; i < 4; ++i)
#pragma unroll
    for (int j = 0; j < 4; ++j) acc[i][j] = (f32x4){0.f, 0.f, 0.f, 0.f};

  // staging: wave w issues 2 global_load_lds per matrix; lane i of issue j
  // covers row (w*2+j)*16 + i/4, 16B chunk i%4 -> lands at ldsbase + i*16.
  const int sr = lane >> 2, sc = lane & 3;
  const u16* Ap = A + (size_t)(bm * 128) * Kdim;
  const u16* Bp = Bt + (size_t)(bn * 128) * Kdim;

  const int nkt = Kdim >> 5;
  for (int kt = 0; kt < nkt; ++kt) {
    const int kb = kt * 32;
#pragma unroll
    for (int j = 0; j < 2; ++j) {
      const int rb = w * 2 + j;                  // 16-row group 0..7
      u16* lA = &As[rb * 512];
      u16* lB = &Bs[rb * 512];
      const u16* gA = Ap + (size_t)(rb * 16 + sr) * Kdim + kb + sc * 8;
      const u16* gB = Bp + (size_t)(rb * 16 + sr) * Kdim + kb + sc * 8;
      GLOAD_LDS16(gA, lA);
      GLOAD_LDS16(gB, lB);
    }
    __syncthreads();
    bf16x8 af[4], bfr[4];
#pragma unroll
    for (int ti = 0; ti < 4; ++ti)
      af[ti] = *(const bf16x8*)&As[(wr*64 + ti*16 + l16) * 32 + quad*8];
#pragma unroll
    for (int tj = 0; tj < 4; ++tj)
      bfr[tj] = *(const bf16x8*)&Bs[(wc*64 + tj*16 + l16) * 32 + quad*8];
#pragma unroll
    for (int ti = 0; ti < 4; ++ti)
#pragma unroll
      for (int tj = 0; tj < 4; ++tj)
        acc[ti][tj] = __builtin_amdgcn_mfma_f32_16x16x32_bf16(af[ti], bfr[tj], acc[ti][tj], 0, 0, 0);
    __syncthreads();
  }
  // epilogue: C/D layout col=lane&15, row=quad*4+r (m89/m91-verified mapping)
#pragma unroll
  for (int ti = 0; ti < 4; ++ti) {
    int row = bm*128 + wr*64 + ti*16 + quad*4;
#pragma unroll
    for (int tj = 0; tj < 4; ++tj) {
      int col = bn*128 + wc*64 + tj*16 + l16;
      float bv = bias[col];
#pragma unroll
      for (int r = 0; r < 4; ++r)
        Cout[(size_t)(row + r) * Ndim + col] = acc[ti][tj][r] + bv;
    }
  }
}

// ---------------- per-128-group symmetric int8 fake-quant (q and k) ----------------
__global__ __launch_bounds__(256) void k_quant_rows(const float* __restrict__ in,
                                                    u16* __restrict__ out,
                                                    int instride, int outstride,
                                                    float premul) {
  int wid = (blockIdx.x * 256 + threadIdx.x) >> 6;
  int lane = threadIdx.x & 63;
  int row = wid >> 4, g = wid & 15;
  const float* p = in + (size_t)row * instride + g * 128;
  float2 v = *(const float2*)(p + lane * 2);
  float vx = v.x * premul, vy = v.y * premul;
  float amax = fmaxf(fabsf(vx), fabsf(vy));
#pragma unroll
  for (int off = 32; off; off >>= 1) amax = fmaxf(amax, __shfl_xor(amax, off));
  float s = fmaxf(amax * (1.f / 127.f), 1e-8f);
  float qx = fminf(fmaxf(rintf(vx / s), -127.f), 127.f) * s;
  float qy = fminf(fmaxf(rintf(vy / s), -127.f), 127.f) * s;
  u32 packed = (u32)f2bf(qx) | ((u32)f2bf(qy) << 16);
  *(u32*)(out + (size_t)row * outstride + g * 128 + lane * 2) = packed;
}

__global__ __launch_bounds__(256) void k_zero(float* p, int n) {
  int i = blockIdx.x * 256 + threadIdx.x;
  if (i < n) p[i] = 0.f;
}

// ---------------- per-column |max| of V ----------------
__global__ __launch_bounds__(256) void k_col_absmax(const float* __restrict__ in,
                                                    u32* __restrict__ vmax) {
  int c = blockIdx.x * 256 + threadIdx.x;
  int t0 = blockIdx.y * 64;
  float m = 0.f;
  for (int r = 0; r < 64; ++r)
    m = fmaxf(m, fabsf(in[(size_t)(t0 + r) * 4096 + c]));
  atomicMax(&vmax[c], __float_as_uint(m));   // all values >=0: uint order == float order
}

// ---------------- quantize V and write transposed: Vt[(h*128+d)][token] ----------------
__global__ __launch_bounds__(256) void k_vt_quant(const float* __restrict__ in,
                                                  const float* __restrict__ vmax,
                                                  u16* __restrict__ Vt) {
  __shared__ float tile[32][33];
  int c0 = blockIdx.x * 32;  // d-columns
  int t0 = blockIdx.y * 32;  // tokens
  int tx = threadIdx.x & 31, ty = threadIdx.x >> 5;
#pragma unroll
  for (int i = 0; i < 4; ++i)
    tile[ty + i*8][tx] = in[(size_t)(t0 + ty + i*8) * 4096 + c0 + tx];
  __syncthreads();
#pragma unroll
  for (int i = 0; i < 4; ++i) {
    int d = ty + i*8;
    float s = fmaxf(vmax[c0 + d] * (1.f / 127.f), 1e-8f);
    float q = fminf(fmaxf(rintf(tile[tx][d] / s), -127.f), 127.f) * s;
    Vt[(size_t)(c0 + d) * 1024 + t0 + tx] = f2bf(q);
  }
}

// ---------------- fused attention: block = (head, 32 q-rows), 4 waves ----------------
// S (32x1024) in registers. exp cached back into s_acc (single exp pass).
// PV goes through a 16KB 32x256 chunk buffer, 4 iterations: iteration cc has
// wave w write u for kv [w*256+cc*64, +64), then all waves MFMA their d-slice
// over those 256 tokens. LDS 17.5KB -> occupancy VGPR-bound (3 blocks/CU) vs
// round-1's 64KB (1 block/CU).
__global__ __launch_bounds__(256) void k_attn(const u16* __restrict__ Qq,
                                              const u16* __restrict__ Kq,
                                              const u16* __restrict__ Vt,
                                              u16* __restrict__ O) {
  __shared__ u16 Ub[32 * 256];       // 16KB chunk buffer
  __shared__ float redmax[128];      // [4 waves][32 rows]
  __shared__ float redsum[128];

  const int h = blockIdx.y;
  const int r0 = blockIdx.x * 32;
  const int t = threadIdx.x;
  const int w = t >> 6, lane = t & 63, quad = lane >> 4, l16 = lane & 15;

  const u16* Qh = Qq + (size_t)r0 * 2048 + h * 128;
  const u16* Kh = Kq + h * 128;
  const u16* Vh = Vt + (size_t)h * 128 * 1024;

  // ---- S = Q K^T : wave w owns kv tokens [w*256, w*256+256) ----
  f32x4 s_acc[2][16];
#pragma unroll
  for (int ti = 0; ti < 2; ++ti)
#pragma unroll
    for (int tj = 0; tj < 16; ++tj) s_acc[ti][tj] = (f32x4){0.f, 0.f, 0.f, 0.f};

  for (int ks = 0; ks < 4; ++ks) {
    bf16x8 aq0 = *(const bf16x8*)&Qh[(size_t)(l16)      * 2048 + ks*32 + quad*8];
    bf16x8 aq1 = *(const bf16x8*)&Qh[(size_t)(16 + l16) * 2048 + ks*32 + quad*8];
#pragma unroll
    for (int tj = 0; tj < 16; ++tj) {
      bf16x8 bk = *(const bf16x8*)&Kh[(size_t)(w*256 + tj*16 + l16) * 2048 + ks*32 + quad*8];
      s_acc[0][tj] = __builtin_amdgcn_mfma_f32_16x16x32_bf16(aq0, bk, s_acc[0][tj], 0, 0, 0);
      s_acc[1][tj] = __builtin_amdgcn_mfma_f32_16x16x32_bf16(aq1, bk, s_acc[1][tj], 0, 0, 0);
    }
  }

  // ---- row max (lane's 8 rows: row = ti*16 + quad*4 + r) ----
  float lmax[8];
#pragma unroll
  for (int ti = 0; ti < 2; ++ti)
#pragma unroll
    for (int r = 0; r < 4; ++r) {
      float m = -1e30f;
#pragma unroll
      for (int tj = 0; tj < 16; ++tj) m = fmaxf(m, s_acc[ti][tj][r]);
      lmax[ti*4 + r] = m;
    }
#pragma unroll
  for (int off = 1; off < 16; off <<= 1)
#pragma unroll
    for (int i = 0; i < 8; ++i) lmax[i] = fmaxf(lmax[i], __shfl_xor(lmax[i], off));
  if (l16 == 0)
#pragma unroll
    for (int i = 0; i < 8; ++i)
      redmax[w*32 + (i >> 2)*16 + quad*4 + (i & 3)] = lmax[i];
  __syncthreads();

  // ---- e = exp(s-gm) cached IN PLACE into s_acc; row sums ----
  float gm[8], lsum[8];
#pragma unroll
  for (int i = 0; i < 8; ++i) {
    int row = (i >> 2)*16 + quad*4 + (i & 3);
    gm[i] = fmaxf(fmaxf(redmax[row], redmax[32 + row]),
                  fmaxf(redmax[64 + row], redmax[96 + row]));
    lsum[i] = 0.f;
  }
#pragma unroll
  for (int ti = 0; ti < 2; ++ti)
#pragma unroll
    for (int tj = 0; tj < 16; ++tj)
#pragma unroll
      for (int r = 0; r < 4; ++r) {
        float e = __expf(s_acc[ti][tj][r] - gm[ti*4 + r]);
        s_acc[ti][tj][r] = e;
        lsum[ti*4 + r] += e;
      }
#pragma unroll
  for (int off = 1; off < 16; off <<= 1)
#pragma unroll
    for (int i = 0; i < 8; ++i) lsum[i] += __shfl_xor(lsum[i], off);
  if (l16 == 0)
#pragma unroll
    for (int i = 0; i < 8; ++i)
      redsum[w*32 + (i >> 2)*16 + quad*4 + (i & 3)] = lsum[i];
  __syncthreads();

  float rinv[8];
#pragma unroll
  for (int i = 0; i < 8; ++i) {
    int row = (i >> 2)*16 + quad*4 + (i & 3);
    float l = redsum[row] + redsum[32 + row] + redsum[64 + row] + redsum[96 + row];
    rinv[i] = 1.f / (255.f * l);   // s_p = max(p)/255 = 1/(255*l); 1e-8 floor can't bind
  }

  // ---- chunked PV: 4 iterations x 256 kv tokens through 16KB LDS ----
  f32x4 o_acc[2][2];
#pragma unroll
  for (int ti = 0; ti < 2; ++ti)
#pragma unroll
    for (int tj = 0; tj < 2; ++tj) o_acc[ti][tj] = (f32x4){0.f, 0.f, 0.f, 0.f};

  for (int cc = 0; cc < 4; ++cc) {
    // write u = rint(255*e) for wave's tj in [cc*4, cc*4+4)
    // Ub col = w*64 + tjj*16 + l16 (token = w*256 + cc*64 + tjj*16 + l16)
#pragma unroll
    for (int ti = 0; ti < 2; ++ti)
#pragma unroll
      for (int tjj = 0; tjj < 4; ++tjj) {
        int tj = cc*4 + tjj;
#pragma unroll
        for (int r = 0; r < 4; ++r) {
          int row = ti*16 + quad*4 + r;
          int col = w*64 + tjj*16 + l16;
          float u = rintf(255.f * s_acc[ti][tj][r]);
          int chunk = col >> 3;
          Ub[row*256 + ((chunk ^ (row & 7)) << 3) + (col & 7)] = f2bf(u);
        }
      }
    __syncthreads();
    // PV over these 256 tokens; wave w owns d-cols [w*32, +32)
#pragma unroll
    for (int ks = 0; ks < 8; ++ks) {
      int token_base = (ks >> 1) * 256 + cc * 64 + (ks & 1) * 32;
      bf16x8 au[2];
#pragma unroll
      for (int ti = 0; ti < 2; ++ti) {
        int row = ti*16 + l16;
        int chunk = ks*4 + quad;
        au[ti] = *(const bf16x8*)&Ub[row*256 + ((chunk ^ (row & 7)) << 3)];
      }
#pragma unroll
      for (int tj = 0; tj < 2; ++tj) {
        bf16x8 bv = *(const bf16x8*)&Vh[(size_t)(w*32 + tj*16 + l16) * 1024 + token_base + quad*8];
        o_acc[0][tj] = __builtin_amdgcn_mfma_f32_16x16x32_bf16(au[0], bv, o_acc[0][tj], 0, 0, 0);
        o_acc[1][tj] = __builtin_amdgcn_mfma_f32_16x16x32_bf16(au[1], bv, o_acc[1][tj], 0, 0, 0);
      }
    }
    __syncthreads();
  }

#pragma unroll
  for (int ti = 0; ti < 2; ++ti)
#pragma unroll
    for (int tj = 0; tj < 2; ++tj)
#pragma unroll
      for (int r = 0; r < 4; ++r) {
        int row = ti*16 + quad*4 + r;
        int d = w*32 + tj*16 + l16;
        O[(size_t)(r0 + row) * 2048 + h*128 + d] = f2bf(o_acc[ti][tj][r] * rinv[ti*4 + r]);
      }
}

extern "C" void kernel_launch(void* const* d_in, const int* in_sizes, int n_in,
                              void* d_out, int out_size, void* d_ws, size_t ws_size,
                              hipStream_t stream) {
  const float* x    = (const float*)d_in[0];
  const float* cond = (const float*)d_in[1];
  const float* Wq   = (const float*)d_in[2];
  const float* bq   = (const float*)d_in[3];
  const float* Wkv  = (const float*)d_in[4];
  const float* bkv  = (const float*)d_in[5];
  const float* Wp   = (const float*)d_in[6];
  const float* bp   = (const float*)d_in[7];
  float* out = (float*)d_out;

  char* ws = (char*)d_ws;
  size_t off = 0;
  auto alloc = [&](size_t bytes) -> char* {
    char* p = ws + off;
    off += (bytes + 255) & ~(size_t)255;
    return p;
  };
  u16*   Xb    = (u16*)alloc((size_t)NQ * CDIM * 2);
  u16*   Cb    = (u16*)alloc((size_t)NKV * CDIM * 2);
  u16*   WqT   = (u16*)alloc((size_t)CDIM * CDIM * 2);
  u16*   WkvT  = (u16*)alloc((size_t)2 * CDIM * CDIM * 2);
  u16*   WpT   = (u16*)alloc((size_t)CDIM * CDIM * 2);
  float* Qraw  = (float*)alloc((size_t)NQ * CDIM * 4);
  float* KVraw = (float*)alloc((size_t)NKV * 2 * CDIM * 4);
  u16*   Qq    = (u16*)alloc((size_t)NQ * CDIM * 2);
  u16*   Kq    = (u16*)alloc((size_t)NKV * CDIM * 2);
  u16*   Vt    = (u16*)alloc((size_t)CDIM * NKV * 2);
  float* vmax  = (float*)alloc((size_t)CDIM * 4);
  u16*   Ob    = (u16*)alloc((size_t)NQ * CDIM * 2);

  k_f32_to_bf16<<<NQ * CDIM / 4 / 256, 256, 0, stream>>>(x, Xb, NQ * CDIM / 4);
  k_f32_to_bf16<<<NKV * CDIM / 4 / 256, 256, 0, stream>>>(cond, Cb, NKV * CDIM / 4);
  k_transpose_bf16<<<dim3(CDIM/32, CDIM/32), 256, 0, stream>>>(Wq, WqT, CDIM, CDIM);
  k_transpose_bf16<<<dim3(2*CDIM/32, CDIM/32), 256, 0, stream>>>(Wkv, WkvT, CDIM, 2*CDIM);
  k_transpose_bf16<<<dim3(CDIM/32, CDIM/32), 256, 0, stream>>>(Wp, WpT, CDIM, CDIM);
  k_gemm_bt<<<dim3(CDIM/128, NQ/128), 256, 0, stream>>>(Xb, WqT, bq, Qraw, CDIM, CDIM);
  k_gemm_bt<<<dim3(2*CDIM/128, NKV/128), 256, 0, stream>>>(Cb, WkvT, bkv, KVraw, 2*CDIM, CDIM);
  k_quant_rows<<<NQ * NHEADS / 4, 256, 0, stream>>>(Qraw, Qq, CDIM, CDIM, QSCALE);
  k_quant_rows<<<NKV * NHEADS / 4, 256, 0, stream>>>(KVraw, Kq, 2*CDIM, CDIM, 1.0f);
  k_zero<<<(CDIM + 255) / 256, 256, 0, stream>>>(vmax, CDIM);
  k_col_absmax<<<dim3(CDIM/256, NKV/64), 256, 0, stream>>>(KVraw + CDIM, (u32*)vmax);
  k_vt_quant<<<dim3(CDIM/32, NKV/32), 256, 0, stream>>>(KVraw + CDIM, vmax, Vt);
  k_attn<<<dim3(NQ/32, NHEADS), 256, 0, stream>>>(Qq, Kq, Vt, Ob);
  k_gemm_bt<<<dim3(CDIM/128, NQ/128), 256, 0, stream>>>(Ob, WpT, bp, out, CDIM, CDIM);
}

// Round 3
// 489.588 us; speedup vs baseline: 1.1398x; 1.1061x over previous
//
#include <hip/hip_runtime.h>

typedef unsigned short u16;
typedef unsigned int u32;
typedef __attribute__((ext_vector_type(8))) short bf16x8;
typedef __attribute__((ext_vector_type(4))) float f32x4;

#define NQ 4096      // B*N query tokens
#define NKV 1024     // B*M kv tokens
#define CDIM 2048
#define NHEADS 16
#define HDIM 128
#define QSCALE 0.08838834764831843f  // 1/sqrt(128)

#define GLOAD_LDS16(g, l) __builtin_amdgcn_global_load_lds( \
    (const __attribute__((address_space(1))) unsigned int*)(g), \
    (__attribute__((address_space(3))) unsigned int*)(l), 16, 0, 0)

__device__ __forceinline__ u16 f2bf(float f) {
  union { float f; u32 u; } a; a.f = f;
  u32 r = (a.u + 0x7fffu + ((a.u >> 16) & 1u)) >> 16;   // RNE
  return (u16)r;
}

// ---------------- fp32 -> bf16 flat convert (x4 vectorized) ----------------
__global__ __launch_bounds__(256) void k_f32_to_bf16(const float* __restrict__ in,
                                                     u16* __restrict__ out, int n4) {
  int i = blockIdx.x * 256 + threadIdx.x;
  if (i >= n4) return;
  float4 v = ((const float4*)in)[i];
  uint2 r;
  r.x = (u32)f2bf(v.x) | ((u32)f2bf(v.y) << 16);
  r.y = (u32)f2bf(v.z) | ((u32)f2bf(v.w) << 16);
  ((uint2*)out)[i] = r;
}

// ---------------- transpose fp32 (R x C) -> bf16 (C x R) ----------------
__global__ __launch_bounds__(256) void k_transpose_bf16(const float* __restrict__ in,
                                                        u16* __restrict__ out,
                                                        int R, int Ccols) {
  __shared__ float tile[32][33];
  int c0 = blockIdx.x * 32, r0 = blockIdx.y * 32;
  int tx = threadIdx.x & 31, ty = threadIdx.x >> 5;
#pragma unroll
  for (int i = 0; i < 4; ++i)
    tile[ty + i*8][tx] = in[(size_t)(r0 + ty + i*8) * Ccols + c0 + tx];
  __syncthreads();
#pragma unroll
  for (int i = 0; i < 4; ++i)
    out[(size_t)(c0 + ty + i*8) * R + r0 + tx] = f2bf(tile[tx][ty + i*8]);
}

// ---------------- bf16 MFMA GEMM: C(M,N) = A(M,K) @ Bt(N,K)^T + bias ----------------
__global__ __launch_bounds__(256) void k_gemm_bt(const u16* __restrict__ A,
                                                 const u16* __restrict__ Bt,
                                                 const float* __restrict__ bias,
                                                 float* __restrict__ Cout,
                                                 int Ndim, int Kdim) {
  __shared__ u16 As[128 * 32];
  __shared__ u16 Bs[128 * 32];
  const int bn = blockIdx.x, bm = blockIdx.y;
  const int t = threadIdx.x;
  const int lane = t & 63, w = t >> 6, quad = lane >> 4, l16 = lane & 15;
  const int wr = w >> 1, wc = w & 1;

  f32x4 acc[4][4];
#pragma unroll
  for (int i = 0; i < 4; ++i)
#pragma unroll
    for (int j = 0; j < 4; ++j) acc[i][j] = (f32x4){0.f, 0.f, 0.f, 0.f};

  const int sr = lane >> 2, sc = lane & 3;
  const u16* Ap = A + (size_t)(bm * 128) * Kdim;
  const u16* Bp = Bt + (size_t)(bn * 128) * Kdim;

  const int nkt = Kdim >> 5;
  for (int kt = 0; kt < nkt; ++kt) {
    const int kb = kt * 32;
#pragma unroll
    for (int j = 0; j < 2; ++j) {
      const int rb = w * 2 + j;
      u16* lA = &As[rb * 512];
      u16* lB = &Bs[rb * 512];
      const u16* gA = Ap + (size_t)(rb * 16 + sr) * Kdim + kb + sc * 8;
      const u16* gB = Bp + (size_t)(rb * 16 + sr) * Kdim + kb + sc * 8;
      GLOAD_LDS16(gA, lA);
      GLOAD_LDS16(gB, lB);
    }
    __syncthreads();
    bf16x8 af[4], bfr[4];
#pragma unroll
    for (int ti = 0; ti < 4; ++ti)
      af[ti] = *(const bf16x8*)&As[(wr*64 + ti*16 + l16) * 32 + quad*8];
#pragma unroll
    for (int tj = 0; tj < 4; ++tj)
      bfr[tj] = *(const bf16x8*)&Bs[(wc*64 + tj*16 + l16) * 32 + quad*8];
#pragma unroll
    for (int ti = 0; ti < 4; ++ti)
#pragma unroll
      for (int tj = 0; tj < 4; ++tj)
        acc[ti][tj] = __builtin_amdgcn_mfma_f32_16x16x32_bf16(af[ti], bfr[tj], acc[ti][tj], 0, 0, 0);
    __syncthreads();
  }
#pragma unroll
  for (int ti = 0; ti < 4; ++ti) {
    int row = bm*128 + wr*64 + ti*16 + quad*4;
#pragma unroll
    for (int tj = 0; tj < 4; ++tj) {
      int col = bn*128 + wc*64 + tj*16 + l16;
      float bv = bias[col];
#pragma unroll
      for (int r = 0; r < 4; ++r)
        Cout[(size_t)(row + r) * Ndim + col] = acc[ti][tj][r] + bv;
    }
  }
}

// ---------------- per-128-group symmetric int8 fake-quant (q and k) ----------------
__global__ __launch_bounds__(256) void k_quant_rows(const float* __restrict__ in,
                                                    u16* __restrict__ out,
                                                    int instride, int outstride,
                                                    float premul) {
  int wid = (blockIdx.x * 256 + threadIdx.x) >> 6;
  int lane = threadIdx.x & 63;
  int row = wid >> 4, g = wid & 15;
  const float* p = in + (size_t)row * instride + g * 128;
  float2 v = *(const float2*)(p + lane * 2);
  float vx = v.x * premul, vy = v.y * premul;
  float amax = fmaxf(fabsf(vx), fabsf(vy));
#pragma unroll
  for (int off = 32; off; off >>= 1) amax = fmaxf(amax, __shfl_xor(amax, off));
  float s = fmaxf(amax * (1.f / 127.f), 1e-8f);
  float qx = fminf(fmaxf(rintf(vx / s), -127.f), 127.f) * s;
  float qy = fminf(fmaxf(rintf(vy / s), -127.f), 127.f) * s;
  u32 packed = (u32)f2bf(qx) | ((u32)f2bf(qy) << 16);
  *(u32*)(out + (size_t)row * outstride + g * 128 + lane * 2) = packed;
}

__global__ __launch_bounds__(256) void k_zero(float* p, int n) {
  int i = blockIdx.x * 256 + threadIdx.x;
  if (i < n) p[i] = 0.f;
}

// ---------------- per-column |max| of V ----------------
__global__ __launch_bounds__(256) void k_col_absmax(const float* __restrict__ in,
                                                    u32* __restrict__ vmax) {
  int c = blockIdx.x * 256 + threadIdx.x;
  int t0 = blockIdx.y * 64;
  float m = 0.f;
  for (int r = 0; r < 64; ++r)
    m = fmaxf(m, fabsf(in[(size_t)(t0 + r) * 4096 + c]));
  atomicMax(&vmax[c], __float_as_uint(m));
}

// ---------------- quantize V and write transposed: Vt[(h*128+d)][token] ----------------
__global__ __launch_bounds__(256) void k_vt_quant(const float* __restrict__ in,
                                                  const float* __restrict__ vmax,
                                                  u16* __restrict__ Vt) {
  __shared__ float tile[32][33];
  int c0 = blockIdx.x * 32;
  int t0 = blockIdx.y * 32;
  int tx = threadIdx.x & 31, ty = threadIdx.x >> 5;
#pragma unroll
  for (int i = 0; i < 4; ++i)
    tile[ty + i*8][tx] = in[(size_t)(t0 + ty + i*8) * 4096 + c0 + tx];
  __syncthreads();
#pragma unroll
  for (int i = 0; i < 4; ++i) {
    int d = ty + i*8;
    float s = fmaxf(vmax[c0 + d] * (1.f / 127.f), 1e-8f);
    float q = fminf(fmaxf(rintf(tile[tx][d] / s), -127.f), 127.f) * s;
    Vt[(size_t)(c0 + d) * 1024 + t0 + tx] = f2bf(q);
  }
}

// ---------------- fused attention, two-pass chunked ----------------
// Block = (head, 128 q-rows); 4 waves x 32 q-rows. kv streamed in 16 chunks of 64
// tokens via global_load_lds into XOR-swizzled LDS (granule g stored at g^(row&mask)
// so all b128 fragment reads are 2-way-conflict-free = free per m136).
// Pass 1: exact row max m + online sum l (wave-local: a wave owns its rows x all kv).
// Pass 2: recompute QK^T (bit-identical), u=rint(255*exp(s-m)) -> per-wave swizzled
// LDS tile -> PV MFMA from LDS V. No stored S => ~200 VGPR, 2 waves/SIMD, 2 blocks/CU.
__global__ __launch_bounds__(256) void k_attn(const u16* __restrict__ Qq,
                                              const u16* __restrict__ Kq,
                                              const u16* __restrict__ Vt,
                                              u16* __restrict__ O) {
  __shared__ u16 Ks[64 * 128];     // [tok][dim], granule swizzle g^(tok&15), 16KB
  __shared__ u16 Vs[128 * 64];     // [d][tok],  granule swizzle g^(d&7),   16KB
  __shared__ u16 Ub[4 * 32 * 64];  // per-wave [q][tok], swizzle g^(q&7),   16KB

  const int h = blockIdx.y;
  const int r0 = blockIdx.x * 128;
  const int t = threadIdx.x;
  const int w = t >> 6, lane = t & 63, quad = lane >> 4, l16 = lane & 15;

  const u16* Qh = Qq + (size_t)(r0 + w * 32) * CDIM + h * HDIM;
  const u16* Kh = Kq + h * HDIM;
  const u16* Vh = Vt + (size_t)h * HDIM * NKV;

  // persistent Q fragments: wave's 32 q-rows x full 128 dim (A-layout)
  bf16x8 qf[2][4];
#pragma unroll
  for (int ti = 0; ti < 2; ++ti)
#pragma unroll
    for (int ks = 0; ks < 4; ++ks)
      qf[ti][ks] = *(const bf16x8*)&Qh[(size_t)(ti * 16 + l16) * CDIM + ks * 32 + quad * 8];

  float m[8], l[8];
#pragma unroll
  for (int i = 0; i < 8; ++i) { m[i] = -3e38f; l[i] = 0.f; }

  // ==================== pass 1: m, l ====================
  for (int ck = 0; ck < 16; ++ck) {
    __syncthreads();   // prior chunk's Ks reads done
#pragma unroll
    for (int j = 0; j < 4; ++j) {
      int tl = (w * 4 + j) * 4 + (lane >> 4);          // token-in-chunk 0..63
      int g = (lane & 15) ^ (tl & 15);                 // swizzled global granule
      GLOAD_LDS16(Kh + (size_t)(ck * 64 + tl) * CDIM + g * 8, &Ks[(w * 4 + j) * 512]);
    }
    __syncthreads();

    f32x4 s_acc[2][4];
#pragma unroll
    for (int ti = 0; ti < 2; ++ti)
#pragma unroll
      for (int tj = 0; tj < 4; ++tj) s_acc[ti][tj] = (f32x4){0.f, 0.f, 0.f, 0.f};
#pragma unroll
    for (int ks = 0; ks < 4; ++ks)
#pragma unroll
      for (int tj = 0; tj < 4; ++tj) {
        bf16x8 bk = *(const bf16x8*)&Ks[(tj * 16 + l16) * 128 + (((ks * 4 + quad) ^ l16) << 3)];
        s_acc[0][tj] = __builtin_amdgcn_mfma_f32_16x16x32_bf16(qf[0][ks], bk, s_acc[0][tj], 0, 0, 0);
        s_acc[1][tj] = __builtin_amdgcn_mfma_f32_16x16x32_bf16(qf[1][ks], bk, s_acc[1][tj], 0, 0, 0);
      }

    float cm[8];
#pragma unroll
    for (int i = 0; i < 8; ++i) cm[i] = -3e38f;
#pragma unroll
    for (int ti = 0; ti < 2; ++ti)
#pragma unroll
      for (int tj = 0; tj < 4; ++tj)
#pragma unroll
        for (int r = 0; r < 4; ++r) cm[ti*4 + r] = fmaxf(cm[ti*4 + r], s_acc[ti][tj][r]);
#pragma unroll
    for (int off = 1; off < 16; off <<= 1)
#pragma unroll
      for (int i = 0; i < 8; ++i) cm[i] = fmaxf(cm[i], __shfl_xor(cm[i], off));
#pragma unroll
    for (int i = 0; i < 8; ++i) {
      float mn = fmaxf(m[i], cm[i]);
      l[i] *= __expf(m[i] - mn);
      m[i] = mn;
    }
    float cs[8];
#pragma unroll
    for (int i = 0; i < 8; ++i) cs[i] = 0.f;
#pragma unroll
    for (int ti = 0; ti < 2; ++ti)
#pragma unroll
      for (int tj = 0; tj < 4; ++tj)
#pragma unroll
        for (int r = 0; r < 4; ++r)
          cs[ti*4 + r] += __expf(s_acc[ti][tj][r] - m[ti*4 + r]);
#pragma unroll
    for (int off = 1; off < 16; off <<= 1)
#pragma unroll
      for (int i = 0; i < 8; ++i) cs[i] += __shfl_xor(cs[i], off);
#pragma unroll
    for (int i = 0; i < 8; ++i) l[i] += cs[i];
  }

  float rinv[8];
#pragma unroll
  for (int i = 0; i < 8; ++i) rinv[i] = 1.f / (255.f * l[i]);

  // ==================== pass 2: u + PV ====================
  f32x4 o_acc[2][8];
#pragma unroll
  for (int ti = 0; ti < 2; ++ti)
#pragma unroll
    for (int tj = 0; tj < 8; ++tj) o_acc[ti][tj] = (f32x4){0.f, 0.f, 0.f, 0.f};

  for (int ck = 0; ck < 16; ++ck) {
    __syncthreads();   // prior chunk's Ks/Vs reads done
#pragma unroll
    for (int j = 0; j < 4; ++j) {
      int tl = (w * 4 + j) * 4 + (lane >> 4);
      int g = (lane & 15) ^ (tl & 15);
      GLOAD_LDS16(Kh + (size_t)(ck * 64 + tl) * CDIM + g * 8, &Ks[(w * 4 + j) * 512]);
    }
#pragma unroll
    for (int j = 0; j < 4; ++j) {
      int dl = (w * 4 + j) * 8 + (lane >> 3);          // d-row 0..127
      int g = (lane & 7) ^ (dl & 7);
      GLOAD_LDS16(Vh + (size_t)dl * NKV + ck * 64 + g * 8, &Vs[(w * 4 + j) * 512]);
    }
    __syncthreads();

    f32x4 s_acc[2][4];
#pragma unroll
    for (int ti = 0; ti < 2; ++ti)
#pragma unroll
      for (int tj = 0; tj < 4; ++tj) s_acc[ti][tj] = (f32x4){0.f, 0.f, 0.f, 0.f};
#pragma unroll
    for (int ks = 0; ks < 4; ++ks)
#pragma unroll
      for (int tj = 0; tj < 4; ++tj) {
        bf16x8 bk = *(const bf16x8*)&Ks[(tj * 16 + l16) * 128 + (((ks * 4 + quad) ^ l16) << 3)];
        s_acc[0][tj] = __builtin_amdgcn_mfma_f32_16x16x32_bf16(qf[0][ks], bk, s_acc[0][tj], 0, 0, 0);
        s_acc[1][tj] = __builtin_amdgcn_mfma_f32_16x16x32_bf16(qf[1][ks], bk, s_acc[1][tj], 0, 0, 0);
      }

    // u = rint(255*exp(s-m)) -> per-wave swizzled LDS tile (C-layout -> A-layout)
#pragma unroll
    for (int ti = 0; ti < 2; ++ti)
#pragma unroll
      for (int tj = 0; tj < 4; ++tj)
#pragma unroll
        for (int r = 0; r < 4; ++r) {
          int ql = ti * 16 + quad * 4 + r;
          int tok = tj * 16 + l16;
          float u = rintf(255.f * __expf(s_acc[ti][tj][r] - m[ti*4 + r]));
          Ub[w * 2048 + ql * 64 + ((((tok >> 3) ^ (ql & 7)) << 3) | (tok & 7))] = f2bf(u);
        }
    // wave-local U: in-wave ds ordering (lgkmcnt) is sufficient, no barrier
#pragma unroll
    for (int ks2 = 0; ks2 < 2; ++ks2) {
      bf16x8 au[2];
#pragma unroll
      for (int ti = 0; ti < 2; ++ti) {
        int ql = ti * 16 + l16;
        au[ti] = *(const bf16x8*)&Ub[w * 2048 + ql * 64 + (((ks2 * 4 + quad) ^ (l16 & 7)) << 3)];
      }
#pragma unroll
      for (int tj = 0; tj < 8; ++tj) {
        bf16x8 bv = *(const bf16x8*)&Vs[(tj * 16 + l16) * 64 + (((ks2 * 4 + quad) ^ (l16 & 7)) << 3)];
        o_acc[0][tj] = __builtin_amdgcn_mfma_f32_16x16x32_bf16(au[0], bv, o_acc[0][tj], 0, 0, 0);
        o_acc[1][tj] = __builtin_amdgcn_mfma_f32_16x16x32_bf16(au[1], bv, o_acc[1][tj], 0, 0, 0);
      }
    }
  }

#pragma unroll
  for (int ti = 0; ti < 2; ++ti)
#pragma unroll
    for (int tj = 0; tj < 8; ++tj)
#pragma unroll
      for (int r = 0; r < 4; ++r) {
        int row = r0 + w * 32 + ti * 16 + quad * 4 + r;
        int d = tj * 16 + l16;
        O[(size_t)row * CDIM + h * HDIM + d] = f2bf(o_acc[ti][tj][r] * rinv[ti*4 + r]);
      }
}

extern "C" void kernel_launch(void* const* d_in, const int* in_sizes, int n_in,
                              void* d_out, int out_size, void* d_ws, size_t ws_size,
                              hipStream_t stream) {
  const float* x    = (const float*)d_in[0];
  const float* cond = (const float*)d_in[1];
  const float* Wq   = (const float*)d_in[2];
  const float* bq   = (const float*)d_in[3];
  const float* Wkv  = (const float*)d_in[4];
  const float* bkv  = (const float*)d_in[5];
  const float* Wp   = (const float*)d_in[6];
  const float* bp   = (const float*)d_in[7];
  float* out = (float*)d_out;

  char* ws = (char*)d_ws;
  size_t off = 0;
  auto alloc = [&](size_t bytes) -> char* {
    char* p = ws + off;
    off += (bytes + 255) & ~(size_t)255;
    return p;
  };
  u16*   Xb    = (u16*)alloc((size_t)NQ * CDIM * 2);
  u16*   Cb    = (u16*)alloc((size_t)NKV * CDIM * 2);
  u16*   WqT   = (u16*)alloc((size_t)CDIM * CDIM * 2);
  u16*   WkvT  = (u16*)alloc((size_t)2 * CDIM * CDIM * 2);
  u16*   WpT   = (u16*)alloc((size_t)CDIM * CDIM * 2);
  float* Qraw  = (float*)alloc((size_t)NQ * CDIM * 4);
  float* KVraw = (float*)alloc((size_t)NKV * 2 * CDIM * 4);
  u16*   Qq    = (u16*)alloc((size_t)NQ * CDIM * 2);
  u16*   Kq    = (u16*)alloc((size_t)NKV * CDIM * 2);
  u16*   Vt    = (u16*)alloc((size_t)CDIM * NKV * 2);
  float* vmax  = (float*)alloc((size_t)CDIM * 4);
  u16*   Ob    = (u16*)alloc((size_t)NQ * CDIM * 2);

  k_f32_to_bf16<<<NQ * CDIM / 4 / 256, 256, 0, stream>>>(x, Xb, NQ * CDIM / 4);
  k_f32_to_bf16<<<NKV * CDIM / 4 / 256, 256, 0, stream>>>(cond, Cb, NKV * CDIM / 4);
  k_transpose_bf16<<<dim3(CDIM/32, CDIM/32), 256, 0, stream>>>(Wq, WqT, CDIM, CDIM);
  k_transpose_bf16<<<dim3(2*CDIM/32, CDIM/32), 256, 0, stream>>>(Wkv, WkvT, CDIM, 2*CDIM);
  k_transpose_bf16<<<dim3(CDIM/32, CDIM/32), 256, 0, stream>>>(Wp, WpT, CDIM, CDIM);
  k_gemm_bt<<<dim3(CDIM/128, NQ/128), 256, 0, stream>>>(Xb, WqT, bq, Qraw, CDIM, CDIM);
  k_gemm_bt<<<dim3(2*CDIM/128, NKV/128), 256, 0, stream>>>(Cb, WkvT, bkv, KVraw, 2*CDIM, CDIM);
  k_quant_rows<<<NQ * NHEADS / 4, 256, 0, stream>>>(Qraw, Qq, CDIM, CDIM, QSCALE);
  k_quant_rows<<<NKV * NHEADS / 4, 256, 0, stream>>>(KVraw, Kq, 2*CDIM, CDIM, 1.0f);
  k_zero<<<(CDIM + 255) / 256, 256, 0, stream>>>(vmax, CDIM);
  k_col_absmax<<<dim3(CDIM/256, NKV/64), 256, 0, stream>>>(KVraw + CDIM, (u32*)vmax);
  k_vt_quant<<<dim3(CDIM/32, NKV/32), 256, 0, stream>>>(KVraw + CDIM, vmax, Vt);
  k_attn<<<dim3(NQ/128, NHEADS), 256, 0, stream>>>(Qq, Kq, Vt, Ob);
  k_gemm_bt<<<dim3(CDIM/128, NQ/128), 256, 0, stream>>>(Ob, WpT, bp, out, CDIM, CDIM);
}

// Round 5
// 443.088 us; speedup vs baseline: 1.2594x; 1.1049x over previous
//
#include <hip/hip_runtime.h>

typedef unsigned short u16;
typedef unsigned int u32;
typedef __attribute__((ext_vector_type(8))) short bf16x8;
typedef __attribute__((ext_vector_type(4))) float f32x4;

#define NQ 4096      // B*N query tokens
#define NKV 1024     // B*M kv tokens
#define CDIM 2048
#define NHEADS 16
#define HDIM 128
#define QSCALE 0.08838834764831843f  // 1/sqrt(128)

#define GLOAD_LDS16(g, l) __builtin_amdgcn_global_load_lds( \
    (const __attribute__((address_space(1))) unsigned int*)(g), \
    (__attribute__((address_space(3))) unsigned int*)(l), 16, 0, 0)

__device__ __forceinline__ u16 f2bf(float f) {
  union { float f; u32 u; } a; a.f = f;
  u32 r = (a.u + 0x7fffu + ((a.u >> 16) & 1u)) >> 16;   // RNE
  return (u16)r;
}

// ---------------- fp32 -> bf16 flat convert (x4 vectorized) ----------------
__global__ __launch_bounds__(256) void k_f32_to_bf16(const float* __restrict__ in,
                                                     u16* __restrict__ out, int n4) {
  int i = blockIdx.x * 256 + threadIdx.x;
  if (i >= n4) return;
  float4 v = ((const float4*)in)[i];
  uint2 r;
  r.x = (u32)f2bf(v.x) | ((u32)f2bf(v.y) << 16);
  r.y = (u32)f2bf(v.z) | ((u32)f2bf(v.w) << 16);
  ((uint2*)out)[i] = r;
}

// ---------------- transpose fp32 (R x C) -> bf16 (C x R) ----------------
__global__ __launch_bounds__(256) void k_transpose_bf16(const float* __restrict__ in,
                                                        u16* __restrict__ out,
                                                        int R, int Ccols) {
  __shared__ float tile[32][33];
  int c0 = blockIdx.x * 32, r0 = blockIdx.y * 32;
  int tx = threadIdx.x & 31, ty = threadIdx.x >> 5;
#pragma unroll
  for (int i = 0; i < 4; ++i)
    tile[ty + i*8][tx] = in[(size_t)(r0 + ty + i*8) * Ccols + c0 + tx];
  __syncthreads();
#pragma unroll
  for (int i = 0; i < 4; ++i)
    out[(size_t)(c0 + ty + i*8) * R + r0 + tx] = f2bf(tile[tx][ty + i*8]);
}

// ---------------- bf16 MFMA GEMM: C(M,N) = A(M,K) @ Bt(N,K)^T + bias ----------------
__global__ __launch_bounds__(256) void k_gemm_bt(const u16* __restrict__ A,
                                                 const u16* __restrict__ Bt,
                                                 const float* __restrict__ bias,
                                                 float* __restrict__ Cout,
                                                 int Ndim, int Kdim) {
  __shared__ u16 As[128 * 32];
  __shared__ u16 Bs[128 * 32];
  const int bn = blockIdx.x, bm = blockIdx.y;
  const int t = threadIdx.x;
  const int lane = t & 63, w = t >> 6, quad = lane >> 4, l16 = lane & 15;
  const int wr = w >> 1, wc = w & 1;

  f32x4 acc[4][4];
#pragma unroll
  for (int i = 0; i < 4; ++i)
#pragma unroll
    for (int j = 0; j < 4; ++j) acc[i][j] = (f32x4){0.f, 0.f, 0.f, 0.f};

  const int sr = lane >> 2, sc = lane & 3;
  const u16* Ap = A + (size_t)(bm * 128) * Kdim;
  const u16* Bp = Bt + (size_t)(bn * 128) * Kdim;

  const int nkt = Kdim >> 5;
  for (int kt = 0; kt < nkt; ++kt) {
    const int kb = kt * 32;
#pragma unroll
    for (int j = 0; j < 2; ++j) {
      const int rb = w * 2 + j;
      u16* lA = &As[rb * 512];
      u16* lB = &Bs[rb * 512];
      const u16* gA = Ap + (size_t)(rb * 16 + sr) * Kdim + kb + sc * 8;
      const u16* gB = Bp + (size_t)(rb * 16 + sr) * Kdim + kb + sc * 8;
      GLOAD_LDS16(gA, lA);
      GLOAD_LDS16(gB, lB);
    }
    __syncthreads();
    bf16x8 af[4], bfr[4];
#pragma unroll
    for (int ti = 0; ti < 4; ++ti)
      af[ti] = *(const bf16x8*)&As[(wr*64 + ti*16 + l16) * 32 + quad*8];
#pragma unroll
    for (int tj = 0; tj < 4; ++tj)
      bfr[tj] = *(const bf16x8*)&Bs[(wc*64 + tj*16 + l16) * 32 + quad*8];
#pragma unroll
    for (int ti = 0; ti < 4; ++ti)
#pragma unroll
      for (int tj = 0; tj < 4; ++tj)
        acc[ti][tj] = __builtin_amdgcn_mfma_f32_16x16x32_bf16(af[ti], bfr[tj], acc[ti][tj], 0, 0, 0);
    __syncthreads();
  }
#pragma unroll
  for (int ti = 0; ti < 4; ++ti) {
    int row = bm*128 + wr*64 + ti*16 + quad*4;
#pragma unroll
    for (int tj = 0; tj < 4; ++tj) {
      int col = bn*128 + wc*64 + tj*16 + l16;
      float bv = bias[col];
#pragma unroll
      for (int r = 0; r < 4; ++r)
        Cout[(size_t)(row + r) * Ndim + col] = acc[ti][tj][r] + bv;
    }
  }
}

// ---------------- per-128-group symmetric int8 fake-quant (q and k) ----------------
__global__ __launch_bounds__(256) void k_quant_rows(const float* __restrict__ in,
                                                    u16* __restrict__ out,
                                                    int instride, int outstride,
                                                    float premul) {
  int wid = (blockIdx.x * 256 + threadIdx.x) >> 6;
  int lane = threadIdx.x & 63;
  int row = wid >> 4, g = wid & 15;
  const float* p = in + (size_t)row * instride + g * 128;
  float2 v = *(const float2*)(p + lane * 2);
  float vx = v.x * premul, vy = v.y * premul;
  float amax = fmaxf(fabsf(vx), fabsf(vy));
#pragma unroll
  for (int off = 32; off; off >>= 1) amax = fmaxf(amax, __shfl_xor(amax, off));
  float s = fmaxf(amax * (1.f / 127.f), 1e-8f);
  float qx = fminf(fmaxf(rintf(vx / s), -127.f), 127.f) * s;
  float qy = fminf(fmaxf(rintf(vy / s), -127.f), 127.f) * s;
  u32 packed = (u32)f2bf(qx) | ((u32)f2bf(qy) << 16);
  *(u32*)(out + (size_t)row * outstride + g * 128 + lane * 2) = packed;
}

__global__ __launch_bounds__(256) void k_zero(float* p, int n) {
  int i = blockIdx.x * 256 + threadIdx.x;
  if (i < n) p[i] = 0.f;
}

// ---------------- per-column |max| of V ----------------
__global__ __launch_bounds__(256) void k_col_absmax(const float* __restrict__ in,
                                                    u32* __restrict__ vmax) {
  int c = blockIdx.x * 256 + threadIdx.x;
  int t0 = blockIdx.y * 64;
  float m = 0.f;
  for (int r = 0; r < 64; ++r)
    m = fmaxf(m, fabsf(in[(size_t)(t0 + r) * 4096 + c]));
  atomicMax(&vmax[c], __float_as_uint(m));
}

// ---------------- quantize V and write transposed: Vt[(h*128+d)][token] ----------------
__global__ __launch_bounds__(256) void k_vt_quant(const float* __restrict__ in,
                                                  const float* __restrict__ vmax,
                                                  u16* __restrict__ Vt) {
  __shared__ float tile[32][33];
  int c0 = blockIdx.x * 32;
  int t0 = blockIdx.y * 32;
  int tx = threadIdx.x & 31, ty = threadIdx.x >> 5;
#pragma unroll
  for (int i = 0; i < 4; ++i)
    tile[ty + i*8][tx] = in[(size_t)(t0 + ty + i*8) * 4096 + c0 + tx];
  __syncthreads();
#pragma unroll
  for (int i = 0; i < 4; ++i) {
    int d = ty + i*8;
    float s = fmaxf(vmax[c0 + d] * (1.f / 127.f), 1e-8f);
    float q = fminf(fmaxf(rintf(tile[tx][d] / s), -127.f), 127.f) * s;
    Vt[(size_t)(c0 + d) * 1024 + t0 + tx] = f2bf(q);
  }
}

// ---------------- attention pass 1: row max m + online sum l ----------------
// Block = (head, 64 q-rows); 4 waves x 16 q-rows. K streamed in 16 chunks of 64
// tokens, round-3-proven two-barrier pattern (issue -> barrier -> compute).
// ~70 VGPR, launch_bounds(256,4) -> 4 blocks/CU; LDS 16KB. Latency hidden by TLP.
__global__ __launch_bounds__(256, 4) void k_attn_ml(const u16* __restrict__ Qq,
                                                    const u16* __restrict__ Kq,
                                                    float* __restrict__ mg,
                                                    float* __restrict__ rg) {
  __shared__ u16 Ks[64 * 128];   // granule swizzle g^(tok&15), 16KB

  const int h = blockIdx.y;
  const int r0 = blockIdx.x * 64;
  const int t = threadIdx.x;
  const int w = t >> 6, lane = t & 63, quad = lane >> 4, l16 = lane & 15;

  const u16* Qh = Qq + (size_t)(r0 + w * 16) * CDIM + h * HDIM;
  const u16* Kh = Kq + h * HDIM;

  bf16x8 qf[4];
#pragma unroll
  for (int ks = 0; ks < 4; ++ks)
    qf[ks] = *(const bf16x8*)&Qh[(size_t)l16 * CDIM + ks * 32 + quad * 8];

  float m[4], l[4];
#pragma unroll
  for (int i = 0; i < 4; ++i) { m[i] = -3e38f; l[i] = 0.f; }

  const int tl = (w * 4) * 4 + (lane >> 4);
  const int gsw = (lane & 15);

  for (int ck = 0; ck < 16; ++ck) {
    __syncthreads();   // prior chunk's Ks reads done
#pragma unroll
    for (int j = 0; j < 4; ++j) {
      int tok = tl + j * 4;
      int g = gsw ^ (tok & 15);
      GLOAD_LDS16(Kh + (size_t)(ck * 64 + tok) * CDIM + g * 8, &Ks[(w * 4 + j) * 512]);
    }
    __syncthreads();   // loads drained

    f32x4 s_acc[4];
#pragma unroll
    for (int tj = 0; tj < 4; ++tj) s_acc[tj] = (f32x4){0.f, 0.f, 0.f, 0.f};
#pragma unroll
    for (int ks = 0; ks < 4; ++ks)
#pragma unroll
      for (int tj = 0; tj < 4; ++tj) {
        bf16x8 bk = *(const bf16x8*)&Ks[(tj * 16 + l16) * 128 + (((ks * 4 + quad) ^ l16) << 3)];
        s_acc[tj] = __builtin_amdgcn_mfma_f32_16x16x32_bf16(qf[ks], bk, s_acc[tj], 0, 0, 0);
      }

    float cm[4];
#pragma unroll
    for (int r = 0; r < 4; ++r)
      cm[r] = fmaxf(fmaxf(s_acc[0][r], s_acc[1][r]), fmaxf(s_acc[2][r], s_acc[3][r]));
#pragma unroll
    for (int off = 1; off < 16; off <<= 1)
#pragma unroll
      for (int r = 0; r < 4; ++r) cm[r] = fmaxf(cm[r], __shfl_xor(cm[r], off));
#pragma unroll
    for (int r = 0; r < 4; ++r) {
      float mn = fmaxf(m[r], cm[r]);
      l[r] *= __expf(m[r] - mn);
      m[r] = mn;
    }
    float cs[4];
#pragma unroll
    for (int r = 0; r < 4; ++r)
      cs[r] = __expf(s_acc[0][r] - m[r]) + __expf(s_acc[1][r] - m[r]) +
              __expf(s_acc[2][r] - m[r]) + __expf(s_acc[3][r] - m[r]);
#pragma unroll
    for (int off = 1; off < 16; off <<= 1)
#pragma unroll
      for (int r = 0; r < 4; ++r) cs[r] += __shfl_xor(cs[r], off);
#pragma unroll
    for (int r = 0; r < 4; ++r) l[r] += cs[r];
  }

  if (l16 == 0) {
#pragma unroll
    for (int r = 0; r < 4; ++r) {
      int q = r0 + w * 16 + quad * 4 + r;
      mg[h * NQ + q] = m[r];
      rg[h * NQ + q] = 1.f / (255.f * l[r]);   // s_p = 1/(255*l); 1e-8 floor can't bind
    }
  }
}

// ---------------- attention pass 2: recompute QK^T, u, PV ----------------
// Block = (head, 128 q-rows); 4 waves x 32 q-rows, per-wave full-d PV.
// Two-barrier chunk pattern (round-3-proven). u = rint(255*exp(s-m)) with FINAL m
// from pass 1 -> bit-identical to round 3. launch_bounds(256,2); LDS 48KB -> 2 blocks/CU.
__global__ __launch_bounds__(256, 2) void k_attn_pv(const u16* __restrict__ Qq,
                                                    const u16* __restrict__ Kq,
                                                    const u16* __restrict__ Vt,
                                                    const float* __restrict__ mg,
                                                    const float* __restrict__ rg,
                                                    u16* __restrict__ O) {
  __shared__ u16 Ks[64 * 128];     // swizzle g^(tok&15), 16KB
  __shared__ u16 Vs[128 * 64];     // swizzle g^(d&7),   16KB
  __shared__ u16 Ub[4 * 32 * 64];  // per-wave u tile, swizzle g^(q&7), 16KB

  const int h = blockIdx.y;
  const int r0 = blockIdx.x * 128;
  const int t = threadIdx.x;
  const int w = t >> 6, lane = t & 63, quad = lane >> 4, l16 = lane & 15;

  const u16* Qh = Qq + (size_t)(r0 + w * 32) * CDIM + h * HDIM;
  const u16* Kh = Kq + h * HDIM;
  const u16* Vh = Vt + (size_t)h * HDIM * NKV;

  bf16x8 qf[2][4];
#pragma unroll
  for (int ti = 0; ti < 2; ++ti)
#pragma unroll
    for (int ks = 0; ks < 4; ++ks)
      qf[ti][ks] = *(const bf16x8*)&Qh[(size_t)(ti * 16 + l16) * CDIM + ks * 32 + quad * 8];

  float m[8], rinv[8];
#pragma unroll
  for (int i = 0; i < 8; ++i) {
    int q = r0 + w * 32 + (i >> 2) * 16 + quad * 4 + (i & 3);
    m[i] = mg[h * NQ + q];
    rinv[i] = rg[h * NQ + q];
  }

  f32x4 o_acc[2][8];
#pragma unroll
  for (int ti = 0; ti < 2; ++ti)
#pragma unroll
    for (int tj = 0; tj < 8; ++tj) o_acc[ti][tj] = (f32x4){0.f, 0.f, 0.f, 0.f};

  const int ktl = (w * 4) * 4 + (lane >> 4);
  const int kg = (lane & 15);
  const int vdl = (w * 4) * 8 + (lane >> 3);
  const int vg = (lane & 7);

  for (int ck = 0; ck < 16; ++ck) {
    __syncthreads();   // prior chunk's Ks/Vs reads done
#pragma unroll
    for (int j = 0; j < 4; ++j) {
      int tok = ktl + j * 4;
      GLOAD_LDS16(Kh + (size_t)(ck * 64 + tok) * CDIM + (kg ^ (tok & 15)) * 8,
                  &Ks[(w * 4 + j) * 512]);
    }
#pragma unroll
    for (int j = 0; j < 4; ++j) {
      int dl = vdl + j * 8;
      GLOAD_LDS16(Vh + (size_t)dl * NKV + ck * 64 + (vg ^ (dl & 7)) * 8,
                  &Vs[(w * 4 + j) * 512]);
    }
    __syncthreads();   // loads drained

    f32x4 s_acc[2][4];
#pragma unroll
    for (int ti = 0; ti < 2; ++ti)
#pragma unroll
      for (int tj = 0; tj < 4; ++tj) s_acc[ti][tj] = (f32x4){0.f, 0.f, 0.f, 0.f};
#pragma unroll
    for (int ks = 0; ks < 4; ++ks)
#pragma unroll
      for (int tj = 0; tj < 4; ++tj) {
        bf16x8 bk = *(const bf16x8*)&Ks[(tj * 16 + l16) * 128 + (((ks * 4 + quad) ^ l16) << 3)];
        s_acc[0][tj] = __builtin_amdgcn_mfma_f32_16x16x32_bf16(qf[0][ks], bk, s_acc[0][tj], 0, 0, 0);
        s_acc[1][tj] = __builtin_amdgcn_mfma_f32_16x16x32_bf16(qf[1][ks], bk, s_acc[1][tj], 0, 0, 0);
      }

    // u = rint(255*exp(s-m)) -> per-wave swizzled LDS tile (C-layout -> A-layout)
#pragma unroll
    for (int ti = 0; ti < 2; ++ti)
#pragma unroll
      for (int tj = 0; tj < 4; ++tj)
#pragma unroll
        for (int r = 0; r < 4; ++r) {
          int ql = ti * 16 + quad * 4 + r;
          int tok = tj * 16 + l16;
          float u = rintf(255.f * __expf(s_acc[ti][tj][r] - m[ti*4 + r]));
          Ub[w * 2048 + ql * 64 + ((((tok >> 3) ^ (ql & 7)) << 3) | (tok & 7))] = f2bf(u);
        }
    // wave-local U: in-wave ds ordering (lgkmcnt) suffices, no barrier
#pragma unroll
    for (int ks2 = 0; ks2 < 2; ++ks2) {
      bf16x8 au[2];
#pragma unroll
      for (int ti = 0; ti < 2; ++ti) {
        int ql = ti * 16 + l16;
        au[ti] = *(const bf16x8*)&Ub[w * 2048 + ql * 64 + (((ks2 * 4 + quad) ^ (l16 & 7)) << 3)];
      }
#pragma unroll
      for (int tj = 0; tj < 8; ++tj) {
        bf16x8 bv = *(const bf16x8*)&Vs[(tj * 16 + l16) * 64 + (((ks2 * 4 + quad) ^ (l16 & 7)) << 3)];
        o_acc[0][tj] = __builtin_amdgcn_mfma_f32_16x16x32_bf16(au[0], bv, o_acc[0][tj], 0, 0, 0);
        o_acc[1][tj] = __builtin_amdgcn_mfma_f32_16x16x32_bf16(au[1], bv, o_acc[1][tj], 0, 0, 0);
      }
    }
  }

#pragma unroll
  for (int ti = 0; ti < 2; ++ti)
#pragma unroll
    for (int tj = 0; tj < 8; ++tj)
#pragma unroll
      for (int r = 0; r < 4; ++r) {
        int row = r0 + w * 32 + ti * 16 + quad * 4 + r;
        int d = tj * 16 + l16;
        O[(size_t)row * CDIM + h * HDIM + d] = f2bf(o_acc[ti][tj][r] * rinv[ti*4 + r]);
      }
}

extern "C" void kernel_launch(void* const* d_in, const int* in_sizes, int n_in,
                              void* d_out, int out_size, void* d_ws, size_t ws_size,
                              hipStream_t stream) {
  const float* x    = (const float*)d_in[0];
  const float* cond = (const float*)d_in[1];
  const float* Wq   = (const float*)d_in[2];
  const float* bq   = (const float*)d_in[3];
  const float* Wkv  = (const float*)d_in[4];
  const float* bkv  = (const float*)d_in[5];
  const float* Wp   = (const float*)d_in[6];
  const float* bp   = (const float*)d_in[7];
  float* out = (float*)d_out;

  char* ws = (char*)d_ws;
  size_t off = 0;
  auto alloc = [&](size_t bytes) -> char* {
    char* p = ws + off;
    off += (bytes + 255) & ~(size_t)255;
    return p;
  };
  u16*   Xb    = (u16*)alloc((size_t)NQ * CDIM * 2);
  u16*   Cb    = (u16*)alloc((size_t)NKV * CDIM * 2);
  u16*   WqT   = (u16*)alloc((size_t)CDIM * CDIM * 2);
  u16*   WkvT  = (u16*)alloc((size_t)2 * CDIM * CDIM * 2);
  u16*   WpT   = (u16*)alloc((size_t)CDIM * CDIM * 2);
  float* Qraw  = (float*)alloc((size_t)NQ * CDIM * 4);
  float* KVraw = (float*)alloc((size_t)NKV * 2 * CDIM * 4);
  u16*   Qq    = (u16*)alloc((size_t)NQ * CDIM * 2);
  u16*   Kq    = (u16*)alloc((size_t)NKV * CDIM * 2);
  u16*   Vt    = (u16*)alloc((size_t)CDIM * NKV * 2);
  float* vmax  = (float*)alloc((size_t)CDIM * 4);
  u16*   Ob    = (u16*)alloc((size_t)NQ * CDIM * 2);
  // mg/rg ALIAS Qraw (dead after k_quant_rows) — no workspace growth vs round 3.
  float* mg    = Qraw;                          // 65536 floats
  float* rg    = Qraw + (size_t)NHEADS * NQ;    // 65536 floats (Qraw holds 8M floats)

  k_f32_to_bf16<<<NQ * CDIM / 4 / 256, 256, 0, stream>>>(x, Xb, NQ * CDIM / 4);
  k_f32_to_bf16<<<NKV * CDIM / 4 / 256, 256, 0, stream>>>(cond, Cb, NKV * CDIM / 4);
  k_transpose_bf16<<<dim3(CDIM/32, CDIM/32), 256, 0, stream>>>(Wq, WqT, CDIM, CDIM);
  k_transpose_bf16<<<dim3(2*CDIM/32, CDIM/32), 256, 0, stream>>>(Wkv, WkvT, CDIM, 2*CDIM);
  k_transpose_bf16<<<dim3(CDIM/32, CDIM/32), 256, 0, stream>>>(Wp, WpT, CDIM, CDIM);
  k_gemm_bt<<<dim3(CDIM/128, NQ/128), 256, 0, stream>>>(Xb, WqT, bq, Qraw, CDIM, CDIM);
  k_gemm_bt<<<dim3(2*CDIM/128, NKV/128), 256, 0, stream>>>(Cb, WkvT, bkv, KVraw, 2*CDIM, CDIM);
  k_quant_rows<<<NQ * NHEADS / 4, 256, 0, stream>>>(Qraw, Qq, CDIM, CDIM, QSCALE);
  k_quant_rows<<<NKV * NHEADS / 4, 256, 0, stream>>>(KVraw, Kq, 2*CDIM, CDIM, 1.0f);
  k_zero<<<(CDIM + 255) / 256, 256, 0, stream>>>(vmax, CDIM);
  k_col_absmax<<<dim3(CDIM/256, NKV/64), 256, 0, stream>>>(KVraw + CDIM, (u32*)vmax);
  k_vt_quant<<<dim3(CDIM/32, NKV/32), 256, 0, stream>>>(KVraw + CDIM, vmax, Vt);
  k_attn_ml<<<dim3(NQ/64, NHEADS), 256, 0, stream>>>(Qq, Kq, mg, rg);
  k_attn_pv<<<dim3(NQ/128, NHEADS), 256, 0, stream>>>(Qq, Kq, Vt, mg, rg, Ob);
  k_gemm_bt<<<dim3(CDIM/128, NQ/128), 256, 0, stream>>>(Ob, WpT, bp, out, CDIM, CDIM);
}

// Round 6
// 385.622 us; speedup vs baseline: 1.4471x; 1.1490x over previous
//
#include <hip/hip_runtime.h>

typedef unsigned short u16;
typedef unsigned int u32;
typedef __attribute__((ext_vector_type(8))) short bf16x8;
typedef __attribute__((ext_vector_type(4))) float f32x4;

#define NQ 4096      // B*N query tokens
#define NKV 1024     // B*M kv tokens
#define CDIM 2048
#define NHEADS 16
#define HDIM 128
#define QSCALE 0.08838834764831843f  // 1/sqrt(128)

#define GLOAD_LDS16(g, l) __builtin_amdgcn_global_load_lds( \
    (const __attribute__((address_space(1))) unsigned int*)(g), \
    (__attribute__((address_space(3))) unsigned int*)(l), 16, 0, 0)

__device__ __forceinline__ u16 f2bf(float f) {
  union { float f; u32 u; } a; a.f = f;
  u32 r = (a.u + 0x7fffu + ((a.u >> 16) & 1u)) >> 16;   // RNE
  return (u16)r;
}

// ---------------- fused fp32 -> bf16 convert of x and cond ----------------
__global__ __launch_bounds__(256) void k_convert(const float* __restrict__ x,
                                                 const float* __restrict__ cond,
                                                 u16* __restrict__ Xb,
                                                 u16* __restrict__ Cb) {
  const int nx = NQ * CDIM / 4;
  int i = blockIdx.x * 256 + threadIdx.x;
  const float* in; u16* out; int j;
  if (i < nx) { in = x; out = Xb; j = i; }
  else        { in = cond; out = Cb; j = i - nx; }
  float4 v = ((const float4*)in)[j];
  uint2 r;
  r.x = (u32)f2bf(v.x) | ((u32)f2bf(v.y) << 16);
  r.y = (u32)f2bf(v.z) | ((u32)f2bf(v.w) << 16);
  ((uint2*)out)[j] = r;
}

// ---------------- fused transpose of all three weights (fp32 -> bf16, (K,N)->(N,K)) --
__global__ __launch_bounds__(256) void k_transpose_all(const float* __restrict__ Wq,
                                                       const float* __restrict__ Wkv,
                                                       const float* __restrict__ Wp,
                                                       u16* __restrict__ WqT,
                                                       u16* __restrict__ WkvT,
                                                       u16* __restrict__ WpT) {
  __shared__ float tile[32][33];
  int id = blockIdx.x;
  const float* in; u16* out; int R, Ccols, bx, by;
  if (id < 4096)        { in = Wq;  out = WqT;  R = 2048; Ccols = 2048; bx = id & 63;  by = id >> 6; }
  else if (id < 12288)  { int i = id - 4096;  in = Wkv; out = WkvT; R = 2048; Ccols = 4096; bx = i & 127; by = i >> 7; }
  else                  { int i = id - 12288; in = Wp;  out = WpT;  R = 2048; Ccols = 2048; bx = i & 63;  by = i >> 6; }
  int c0 = bx * 32, r0 = by * 32;
  int tx = threadIdx.x & 31, ty = threadIdx.x >> 5;
#pragma unroll
  for (int i = 0; i < 4; ++i)
    tile[ty + i*8][tx] = in[(size_t)(r0 + ty + i*8) * Ccols + c0 + tx];
  __syncthreads();
#pragma unroll
  for (int i = 0; i < 4; ++i)
    out[(size_t)(c0 + ty + i*8) * R + r0 + tx] = f2bf(tile[tx][ty + i*8]);
}

// ---------------- bf16 MFMA GEMM (out-proj): C = A @ Bt^T + bias, fp32 out ----------
__global__ __launch_bounds__(256) void k_gemm_bt(const u16* __restrict__ A,
                                                 const u16* __restrict__ Bt,
                                                 const float* __restrict__ bias,
                                                 float* __restrict__ Cout,
                                                 int Ndim, int Kdim) {
  __shared__ u16 As[128 * 32];
  __shared__ u16 Bs[128 * 32];
  const int bn = blockIdx.x, bm = blockIdx.y;
  const int t = threadIdx.x;
  const int lane = t & 63, w = t >> 6, quad = lane >> 4, l16 = lane & 15;
  const int wr = w >> 1, wc = w & 1;

  f32x4 acc[4][4];
#pragma unroll
  for (int i = 0; i < 4; ++i)
#pragma unroll
    for (int j = 0; j < 4; ++j) acc[i][j] = (f32x4){0.f, 0.f, 0.f, 0.f};

  const int sr = lane >> 2, sc = lane & 3;
  const u16* Ap = A + (size_t)(bm * 128) * Kdim;
  const u16* Bp = Bt + (size_t)(bn * 128) * Kdim;

  const int nkt = Kdim >> 5;
  for (int kt = 0; kt < nkt; ++kt) {
    const int kb = kt * 32;
#pragma unroll
    for (int j = 0; j < 2; ++j) {
      const int rb = w * 2 + j;
      GLOAD_LDS16(Ap + (size_t)(rb * 16 + sr) * Kdim + kb + sc * 8, &As[rb * 512]);
      GLOAD_LDS16(Bp + (size_t)(rb * 16 + sr) * Kdim + kb + sc * 8, &Bs[rb * 512]);
    }
    __syncthreads();
    bf16x8 af[4], bfr[4];
#pragma unroll
    for (int ti = 0; ti < 4; ++ti)
      af[ti] = *(const bf16x8*)&As[(wr*64 + ti*16 + l16) * 32 + quad*8];
#pragma unroll
    for (int tj = 0; tj < 4; ++tj)
      bfr[tj] = *(const bf16x8*)&Bs[(wc*64 + tj*16 + l16) * 32 + quad*8];
#pragma unroll
    for (int ti = 0; ti < 4; ++ti)
#pragma unroll
      for (int tj = 0; tj < 4; ++tj)
        acc[ti][tj] = __builtin_amdgcn_mfma_f32_16x16x32_bf16(af[ti], bfr[tj], acc[ti][tj], 0, 0, 0);
    __syncthreads();
  }
#pragma unroll
  for (int ti = 0; ti < 4; ++ti) {
    int row = bm*128 + wr*64 + ti*16 + quad*4;
#pragma unroll
    for (int tj = 0; tj < 4; ++tj) {
      int col = bn*128 + wc*64 + tj*16 + l16;
      float bv = bias[col];
#pragma unroll
      for (int r = 0; r < 4; ++r)
        Cout[(size_t)(row + r) * Ndim + col] = acc[ti][tj][r] + bv;
    }
  }
}

// ---------------- fused QKV projection GEMM with quant epilogue ----------------
// One launch, 768 blocks: id<512 -> Q-proj (quant, premul=QSCALE -> Qq bf16);
// id<640 -> K-proj (quant -> Kq bf16); else V-proj (raw fp32 -> KVraw V-half).
// BN=128 == quant group width (head dim), so per-row amax is tile-local:
// in-reg max over tj, shfl over l16, 1KB LDS exchange between the two wc-waves.
// Same fp32 op order as the old k_quant_rows -> bit-identical output.
__global__ __launch_bounds__(256) void k_gemm_qkv(const u16* __restrict__ Xb,
                                                  const u16* __restrict__ Cb,
                                                  const u16* __restrict__ WqT,
                                                  const u16* __restrict__ WkvT,
                                                  const float* __restrict__ bq,
                                                  const float* __restrict__ bkv,
                                                  u16* __restrict__ Qq,
                                                  u16* __restrict__ Kq,
                                                  float* __restrict__ Vraw) {
  __shared__ u16 As[128 * 32];
  __shared__ u16 Bs[128 * 32];
  __shared__ float rmax[2][128];

  const int id = blockIdx.x;
  const u16 *Ain; const u16 *Bt; const float* bias;
  u16* out16 = nullptr; float* outf = nullptr;
  int bm, bn, ostride, ocol;
  float premul = 1.0f;
  if (id < 512) {
    bm = id >> 4; bn = id & 15;
    Ain = Xb; Bt = WqT + (size_t)(bn * 128) * CDIM;
    bias = bq + bn * 128; out16 = Qq; ostride = CDIM; ocol = bn * 128;
    premul = QSCALE;
  } else if (id < 640) {
    int i2 = id - 512; bm = i2 >> 4; bn = i2 & 15;
    Ain = Cb; Bt = WkvT + (size_t)(bn * 128) * CDIM;
    bias = bkv + bn * 128; out16 = Kq; ostride = CDIM; ocol = bn * 128;
  } else {
    int i3 = id - 640; bm = i3 >> 4; bn = i3 & 15;
    Ain = Cb; Bt = WkvT + (size_t)(2048 + bn * 128) * CDIM;
    bias = bkv + 2048 + bn * 128; outf = Vraw; ostride = 2 * CDIM; ocol = 2048 + bn * 128;
  }

  const int t = threadIdx.x;
  const int lane = t & 63, w = t >> 6, quad = lane >> 4, l16 = lane & 15;
  const int wr = w >> 1, wc = w & 1;

  f32x4 acc[4][4];
#pragma unroll
  for (int i = 0; i < 4; ++i)
#pragma unroll
    for (int j = 0; j < 4; ++j) acc[i][j] = (f32x4){0.f, 0.f, 0.f, 0.f};

  const int sr = lane >> 2, sc = lane & 3;
  const u16* Ap = Ain + (size_t)(bm * 128) * CDIM;

  for (int kt = 0; kt < 64; ++kt) {
    const int kb = kt * 32;
#pragma unroll
    for (int j = 0; j < 2; ++j) {
      const int rb = w * 2 + j;
      GLOAD_LDS16(Ap + (size_t)(rb * 16 + sr) * CDIM + kb + sc * 8, &As[rb * 512]);
      GLOAD_LDS16(Bt + (size_t)(rb * 16 + sr) * CDIM + kb + sc * 8, &Bs[rb * 512]);
    }
    __syncthreads();
    bf16x8 af[4], bfr[4];
#pragma unroll
    for (int ti = 0; ti < 4; ++ti)
      af[ti] = *(const bf16x8*)&As[(wr*64 + ti*16 + l16) * 32 + quad*8];
#pragma unroll
    for (int tj = 0; tj < 4; ++tj)
      bfr[tj] = *(const bf16x8*)&Bs[(wc*64 + tj*16 + l16) * 32 + quad*8];
#pragma unroll
    for (int ti = 0; ti < 4; ++ti)
#pragma unroll
      for (int tj = 0; tj < 4; ++tj)
        acc[ti][tj] = __builtin_amdgcn_mfma_f32_16x16x32_bf16(af[ti], bfr[tj], acc[ti][tj], 0, 0, 0);
    __syncthreads();
  }

  float bv[4];
#pragma unroll
  for (int tj = 0; tj < 4; ++tj) bv[tj] = bias[wc*64 + tj*16 + l16];

  if (outf) {
    // V: raw fp32 + bias
#pragma unroll
    for (int ti = 0; ti < 4; ++ti) {
      int row = bm*128 + wr*64 + ti*16 + quad*4;
#pragma unroll
      for (int tj = 0; tj < 4; ++tj) {
        int col = ocol + wc*64 + tj*16 + l16;
#pragma unroll
        for (int r = 0; r < 4; ++r)
          outf[(size_t)(row + r) * ostride + col] = acc[ti][tj][r] + bv[tj];
      }
    }
    return;
  }

  // Q/K: fused per-row-128 symmetric int8 fake-quant (bit-identical to k_quant_rows)
  float amax[4][4];
#pragma unroll
  for (int ti = 0; ti < 4; ++ti)
#pragma unroll
    for (int r = 0; r < 4; ++r) amax[ti][r] = 0.f;
#pragma unroll
  for (int ti = 0; ti < 4; ++ti)
#pragma unroll
    for (int tj = 0; tj < 4; ++tj)
#pragma unroll
      for (int r = 0; r < 4; ++r) {
        float v = (acc[ti][tj][r] + bv[tj]) * premul;
        acc[ti][tj][r] = v;
        amax[ti][r] = fmaxf(amax[ti][r], fabsf(v));
      }
#pragma unroll
  for (int off = 1; off < 16; off <<= 1)
#pragma unroll
    for (int ti = 0; ti < 4; ++ti)
#pragma unroll
      for (int r = 0; r < 4; ++r)
        amax[ti][r] = fmaxf(amax[ti][r], __shfl_xor(amax[ti][r], off));
  if (l16 == 0)
#pragma unroll
    for (int ti = 0; ti < 4; ++ti)
#pragma unroll
      for (int r = 0; r < 4; ++r)
        rmax[wc][wr*64 + ti*16 + quad*4 + r] = amax[ti][r];
  __syncthreads();
#pragma unroll
  for (int ti = 0; ti < 4; ++ti) {
    int rowl = wr*64 + ti*16 + quad*4;
    int row = bm*128 + rowl;
#pragma unroll
    for (int r = 0; r < 4; ++r) {
      float s = fmaxf(fmaxf(rmax[0][rowl + r], rmax[1][rowl + r]) * (1.f / 127.f), 1e-8f);
#pragma unroll
      for (int tj = 0; tj < 4; ++tj) {
        int col = ocol + wc*64 + tj*16 + l16;
        float q = fminf(fmaxf(rintf(acc[ti][tj][r] / s), -127.f), 127.f) * s;
        out16[(size_t)(row + r) * ostride + col] = f2bf(q);
      }
    }
  }
}

__global__ __launch_bounds__(256) void k_zero(float* p, int n) {
  int i = blockIdx.x * 256 + threadIdx.x;
  if (i < n) p[i] = 0.f;
}

// ---------------- per-column |max| of V ----------------
__global__ __launch_bounds__(256) void k_col_absmax(const float* __restrict__ in,
                                                    u32* __restrict__ vmax) {
  int c = blockIdx.x * 256 + threadIdx.x;
  int t0 = blockIdx.y * 64;
  float m = 0.f;
  for (int r = 0; r < 64; ++r)
    m = fmaxf(m, fabsf(in[(size_t)(t0 + r) * 4096 + c]));
  atomicMax(&vmax[c], __float_as_uint(m));
}

// ---------------- quantize V and write transposed: Vt[(h*128+d)][token] ----------------
__global__ __launch_bounds__(256) void k_vt_quant(const float* __restrict__ in,
                                                  const float* __restrict__ vmax,
                                                  u16* __restrict__ Vt) {
  __shared__ float tile[32][33];
  int c0 = blockIdx.x * 32;
  int t0 = blockIdx.y * 32;
  int tx = threadIdx.x & 31, ty = threadIdx.x >> 5;
#pragma unroll
  for (int i = 0; i < 4; ++i)
    tile[ty + i*8][tx] = in[(size_t)(t0 + ty + i*8) * 4096 + c0 + tx];
  __syncthreads();
#pragma unroll
  for (int i = 0; i < 4; ++i) {
    int d = ty + i*8;
    float s = fmaxf(vmax[c0 + d] * (1.f / 127.f), 1e-8f);
    float q = fminf(fmaxf(rintf(tile[tx][d] / s), -127.f), 127.f) * s;
    Vt[(size_t)(c0 + d) * 1024 + t0 + tx] = f2bf(q);
  }
}

// ---------------- attention pass 1: row max m + online sum l ----------------
__global__ __launch_bounds__(256, 4) void k_attn_ml(const u16* __restrict__ Qq,
                                                    const u16* __restrict__ Kq,
                                                    float* __restrict__ mg,
                                                    float* __restrict__ rg) {
  __shared__ u16 Ks[64 * 128];   // granule swizzle g^(tok&15), 16KB

  const int h = blockIdx.y;
  const int r0 = blockIdx.x * 64;
  const int t = threadIdx.x;
  const int w = t >> 6, lane = t & 63, quad = lane >> 4, l16 = lane & 15;

  const u16* Qh = Qq + (size_t)(r0 + w * 16) * CDIM + h * HDIM;
  const u16* Kh = Kq + h * HDIM;

  bf16x8 qf[4];
#pragma unroll
  for (int ks = 0; ks < 4; ++ks)
    qf[ks] = *(const bf16x8*)&Qh[(size_t)l16 * CDIM + ks * 32 + quad * 8];

  float m[4], l[4];
#pragma unroll
  for (int i = 0; i < 4; ++i) { m[i] = -3e38f; l[i] = 0.f; }

  const int tl = (w * 4) * 4 + (lane >> 4);
  const int gsw = (lane & 15);

  for (int ck = 0; ck < 16; ++ck) {
    __syncthreads();
#pragma unroll
    for (int j = 0; j < 4; ++j) {
      int tok = tl + j * 4;
      int g = gsw ^ (tok & 15);
      GLOAD_LDS16(Kh + (size_t)(ck * 64 + tok) * CDIM + g * 8, &Ks[(w * 4 + j) * 512]);
    }
    __syncthreads();

    f32x4 s_acc[4];
#pragma unroll
    for (int tj = 0; tj < 4; ++tj) s_acc[tj] = (f32x4){0.f, 0.f, 0.f, 0.f};
#pragma unroll
    for (int ks = 0; ks < 4; ++ks)
#pragma unroll
      for (int tj = 0; tj < 4; ++tj) {
        bf16x8 bk = *(const bf16x8*)&Ks[(tj * 16 + l16) * 128 + (((ks * 4 + quad) ^ l16) << 3)];
        s_acc[tj] = __builtin_amdgcn_mfma_f32_16x16x32_bf16(qf[ks], bk, s_acc[tj], 0, 0, 0);
      }

    float cm[4];
#pragma unroll
    for (int r = 0; r < 4; ++r)
      cm[r] = fmaxf(fmaxf(s_acc[0][r], s_acc[1][r]), fmaxf(s_acc[2][r], s_acc[3][r]));
#pragma unroll
    for (int off = 1; off < 16; off <<= 1)
#pragma unroll
      for (int r = 0; r < 4; ++r) cm[r] = fmaxf(cm[r], __shfl_xor(cm[r], off));
#pragma unroll
    for (int r = 0; r < 4; ++r) {
      float mn = fmaxf(m[r], cm[r]);
      l[r] *= __expf(m[r] - mn);
      m[r] = mn;
    }
    float cs[4];
#pragma unroll
    for (int r = 0; r < 4; ++r)
      cs[r] = __expf(s_acc[0][r] - m[r]) + __expf(s_acc[1][r] - m[r]) +
              __expf(s_acc[2][r] - m[r]) + __expf(s_acc[3][r] - m[r]);
#pragma unroll
    for (int off = 1; off < 16; off <<= 1)
#pragma unroll
      for (int r = 0; r < 4; ++r) cs[r] += __shfl_xor(cs[r], off);
#pragma unroll
    for (int r = 0; r < 4; ++r) l[r] += cs[r];
  }

  if (l16 == 0) {
#pragma unroll
    for (int r = 0; r < 4; ++r) {
      int q = r0 + w * 16 + quad * 4 + r;
      mg[h * NQ + q] = m[r];
      rg[h * NQ + q] = 1.f / (255.f * l[r]);
    }
  }
}

// ---------------- attention pass 2: recompute QK^T, u, PV ----------------
__global__ __launch_bounds__(256, 2) void k_attn_pv(const u16* __restrict__ Qq,
                                                    const u16* __restrict__ Kq,
                                                    const u16* __restrict__ Vt,
                                                    const float* __restrict__ mg,
                                                    const float* __restrict__ rg,
                                                    u16* __restrict__ O) {
  __shared__ u16 Ks[64 * 128];     // swizzle g^(tok&15), 16KB
  __shared__ u16 Vs[128 * 64];     // swizzle g^(d&7),   16KB
  __shared__ u16 Ub[4 * 32 * 64];  // per-wave u tile, swizzle g^(q&7), 16KB

  const int h = blockIdx.y;
  const int r0 = blockIdx.x * 128;
  const int t = threadIdx.x;
  const int w = t >> 6, lane = t & 63, quad = lane >> 4, l16 = lane & 15;

  const u16* Qh = Qq + (size_t)(r0 + w * 32) * CDIM + h * HDIM;
  const u16* Kh = Kq + h * HDIM;
  const u16* Vh = Vt + (size_t)h * HDIM * NKV;

  bf16x8 qf[2][4];
#pragma unroll
  for (int ti = 0; ti < 2; ++ti)
#pragma unroll
    for (int ks = 0; ks < 4; ++ks)
      qf[ti][ks] = *(const bf16x8*)&Qh[(size_t)(ti * 16 + l16) * CDIM + ks * 32 + quad * 8];

  float m[8], rinv[8];
#pragma unroll
  for (int i = 0; i < 8; ++i) {
    int q = r0 + w * 32 + (i >> 2) * 16 + quad * 4 + (i & 3);
    m[i] = mg[h * NQ + q];
    rinv[i] = rg[h * NQ + q];
  }

  f32x4 o_acc[2][8];
#pragma unroll
  for (int ti = 0; ti < 2; ++ti)
#pragma unroll
    for (int tj = 0; tj < 8; ++tj) o_acc[ti][tj] = (f32x4){0.f, 0.f, 0.f, 0.f};

  const int ktl = (w * 4) * 4 + (lane >> 4);
  const int kg = (lane & 15);
  const int vdl = (w * 4) * 8 + (lane >> 3);
  const int vg = (lane & 7);

  for (int ck = 0; ck < 16; ++ck) {
    __syncthreads();
#pragma unroll
    for (int j = 0; j < 4; ++j) {
      int tok = ktl + j * 4;
      GLOAD_LDS16(Kh + (size_t)(ck * 64 + tok) * CDIM + (kg ^ (tok & 15)) * 8,
                  &Ks[(w * 4 + j) * 512]);
    }
#pragma unroll
    for (int j = 0; j < 4; ++j) {
      int dl = vdl + j * 8;
      GLOAD_LDS16(Vh + (size_t)dl * NKV + ck * 64 + (vg ^ (dl & 7)) * 8,
                  &Vs[(w * 4 + j) * 512]);
    }
    __syncthreads();

    f32x4 s_acc[2][4];
#pragma unroll
    for (int ti = 0; ti < 2; ++ti)
#pragma unroll
      for (int tj = 0; tj < 4; ++tj) s_acc[ti][tj] = (f32x4){0.f, 0.f, 0.f, 0.f};
#pragma unroll
    for (int ks = 0; ks < 4; ++ks)
#pragma unroll
      for (int tj = 0; tj < 4; ++tj) {
        bf16x8 bk = *(const bf16x8*)&Ks[(tj * 16 + l16) * 128 + (((ks * 4 + quad) ^ l16) << 3)];
        s_acc[0][tj] = __builtin_amdgcn_mfma_f32_16x16x32_bf16(qf[0][ks], bk, s_acc[0][tj], 0, 0, 0);
        s_acc[1][tj] = __builtin_amdgcn_mfma_f32_16x16x32_bf16(qf[1][ks], bk, s_acc[1][tj], 0, 0, 0);
      }

#pragma unroll
    for (int ti = 0; ti < 2; ++ti)
#pragma unroll
      for (int tj = 0; tj < 4; ++tj)
#pragma unroll
        for (int r = 0; r < 4; ++r) {
          int ql = ti * 16 + quad * 4 + r;
          int tok = tj * 16 + l16;
          float u = rintf(255.f * __expf(s_acc[ti][tj][r] - m[ti*4 + r]));
          Ub[w * 2048 + ql * 64 + ((((tok >> 3) ^ (ql & 7)) << 3) | (tok & 7))] = f2bf(u);
        }
#pragma unroll
    for (int ks2 = 0; ks2 < 2; ++ks2) {
      bf16x8 au[2];
#pragma unroll
      for (int ti = 0; ti < 2; ++ti) {
        int ql = ti * 16 + l16;
        au[ti] = *(const bf16x8*)&Ub[w * 2048 + ql * 64 + (((ks2 * 4 + quad) ^ (l16 & 7)) << 3)];
      }
#pragma unroll
      for (int tj = 0; tj < 8; ++tj) {
        bf16x8 bv = *(const bf16x8*)&Vs[(tj * 16 + l16) * 64 + (((ks2 * 4 + quad) ^ (l16 & 7)) << 3)];
        o_acc[0][tj] = __builtin_amdgcn_mfma_f32_16x16x32_bf16(au[0], bv, o_acc[0][tj], 0, 0, 0);
        o_acc[1][tj] = __builtin_amdgcn_mfma_f32_16x16x32_bf16(au[1], bv, o_acc[1][tj], 0, 0, 0);
      }
    }
  }

#pragma unroll
  for (int ti = 0; ti < 2; ++ti)
#pragma unroll
    for (int tj = 0; tj < 8; ++tj)
#pragma unroll
      for (int r = 0; r < 4; ++r) {
        int row = r0 + w * 32 + ti * 16 + quad * 4 + r;
        int d = tj * 16 + l16;
        O[(size_t)row * CDIM + h * HDIM + d] = f2bf(o_acc[ti][tj][r] * rinv[ti*4 + r]);
      }
}

extern "C" void kernel_launch(void* const* d_in, const int* in_sizes, int n_in,
                              void* d_out, int out_size, void* d_ws, size_t ws_size,
                              hipStream_t stream) {
  const float* x    = (const float*)d_in[0];
  const float* cond = (const float*)d_in[1];
  const float* Wq   = (const float*)d_in[2];
  const float* bq   = (const float*)d_in[3];
  const float* Wkv  = (const float*)d_in[4];
  const float* bkv  = (const float*)d_in[5];
  const float* Wp   = (const float*)d_in[6];
  const float* bp   = (const float*)d_in[7];
  float* out = (float*)d_out;

  char* ws = (char*)d_ws;
  size_t off = 0;
  auto alloc = [&](size_t bytes) -> char* {
    char* p = ws + off;
    off += (bytes + 255) & ~(size_t)255;
    return p;
  };
  u16*   Xb    = (u16*)alloc((size_t)NQ * CDIM * 2);
  u16*   Cb    = (u16*)alloc((size_t)NKV * CDIM * 2);
  u16*   WqT   = (u16*)alloc((size_t)CDIM * CDIM * 2);
  u16*   WkvT  = (u16*)alloc((size_t)2 * CDIM * CDIM * 2);
  u16*   WpT   = (u16*)alloc((size_t)CDIM * CDIM * 2);
  float* mg    = (float*)alloc((size_t)NHEADS * NQ * 4);
  float* rg    = (float*)alloc((size_t)NHEADS * NQ * 4);
  float* KVraw = (float*)alloc((size_t)NKV * 2 * CDIM * 4);  // only V-half written
  u16*   Qq    = (u16*)alloc((size_t)NQ * CDIM * 2);
  u16*   Kq    = (u16*)alloc((size_t)NKV * CDIM * 2);
  u16*   Vt    = (u16*)alloc((size_t)CDIM * NKV * 2);
  float* vmax  = (float*)alloc((size_t)CDIM * 4);
  u16*   Ob    = (u16*)alloc((size_t)NQ * CDIM * 2);

  k_convert<<<(NQ + NKV) * CDIM / 4 / 256, 256, 0, stream>>>(x, cond, Xb, Cb);
  k_transpose_all<<<16384, 256, 0, stream>>>(Wq, Wkv, Wp, WqT, WkvT, WpT);
  k_gemm_qkv<<<768, 256, 0, stream>>>(Xb, Cb, WqT, WkvT, bq, bkv, Qq, Kq, KVraw);
  k_zero<<<(CDIM + 255) / 256, 256, 0, stream>>>(vmax, CDIM);
  k_col_absmax<<<dim3(CDIM/256, NKV/64), 256, 0, stream>>>(KVraw + CDIM, (u32*)vmax);
  k_vt_quant<<<dim3(CDIM/32, NKV/32), 256, 0, stream>>>(KVraw + CDIM, vmax, Vt);
  k_attn_ml<<<dim3(NQ/64, NHEADS), 256, 0, stream>>>(Qq, Kq, mg, rg);
  k_attn_pv<<<dim3(NQ/128, NHEADS), 256, 0, stream>>>(Qq, Kq, Vt, mg, rg, Ob);
  k_gemm_bt<<<dim3(CDIM/128, NQ/128), 256, 0, stream>>>(Ob, WpT, bp, out, CDIM, CDIM);
}